// Round 1
// baseline (1034.576 us; speedup 1.0000x reference)
//
#include <hip/hip_runtime.h>
#include <math.h>

#define B_      4
#define C_      256
#define NH      8
#define HD      32
#define WINNUM  49
#define LWIN    3136
#define NTOK    3137
#define NPIX    12544     // B * 56 * 56
#define MROWS   12548     // NPIX + 4 cls rows
#define SCALE   0.0625f   // 256^-0.5

// ---------------------------------------------------------------------------
// Kernel A: qkv = [x; cls] @ Wqkv + bqkv, scattered to window-ordered layout
// (B, Nh, 3137, 32). q pre-scaled by SCALE.
// ---------------------------------------------------------------------------
__global__ __launch_bounds__(256)
void qkv_gemm(const float* __restrict__ x, const float* __restrict__ cls,
              const float* __restrict__ Wqkv, const float* __restrict__ bqkv,
              float* __restrict__ qg, float* __restrict__ kg, float* __restrict__ vg)
{
    __shared__ float As[64][16];
    __shared__ float Bs[16][64];
    const int m0 = blockIdx.y * 64;
    const int n0 = blockIdx.x * 64;
    const int tid = threadIdx.x;
    const int ty = tid >> 4, tx = tid & 15;
    const int lr = tid >> 2, lk = (tid & 3) * 4;      // As load: row, col4
    const int lkb = tid >> 4, lcb = (tid & 15) * 4;   // Bs load: row, col4
    float acc[4][4] = {};

    for (int k0 = 0; k0 < 256; k0 += 16) {
        int m = m0 + lr;
        float4 av = make_float4(0.f, 0.f, 0.f, 0.f);
        if (m < MROWS) {
            const float* src = (m < NPIX) ? (x + (size_t)m * 256)
                                          : (cls + (size_t)(m - NPIX) * 256);
            av = *(const float4*)(src + k0 + lk);
        }
        *(float4*)&As[lr][lk] = av;
        *(float4*)&Bs[lkb][lcb] = *(const float4*)(Wqkv + (size_t)(k0 + lkb) * 768 + n0 + lcb);
        __syncthreads();
#pragma unroll
        for (int kk = 0; kk < 16; ++kk) {
            float a[4], bb[4];
#pragma unroll
            for (int i = 0; i < 4; ++i) a[i] = As[ty * 4 + i][kk];
#pragma unroll
            for (int j = 0; j < 4; ++j) bb[j] = Bs[kk][tx * 4 + j];
#pragma unroll
            for (int i = 0; i < 4; ++i)
#pragma unroll
                for (int j = 0; j < 4; ++j) acc[i][j] += a[i] * bb[j];
        }
        __syncthreads();
    }

#pragma unroll
    for (int i = 0; i < 4; ++i) {
        int m = m0 + ty * 4 + i;
        if (m >= MROWS) continue;
        int b, tok;
        if (m < NPIX) {
            b = m / LWIN;
            int p = m % LWIN;
            int h = p / 56, w = p % 56;
            tok = ((h >> 3) * 7 + (w >> 3)) * 64 + ((h & 7) << 3) + (w & 7);
        } else {
            b = m - NPIX; tok = LWIN;
        }
#pragma unroll
        for (int j = 0; j < 4; ++j) {
            int n = n0 + tx * 4 + j;
            float val = acc[i][j] + bqkv[n];
            int part = n >> 8;
            int c = n & 255;
            int nh = c >> 5, d = c & 31;
            size_t dst = ((size_t)(b * NH + nh) * NTOK + tok) * HD + d;
            if (part == 0)       qg[dst] = val * SCALE;
            else if (part == 1)  kg[dst] = val;
            else                 vg[dst] = val;
        }
    }
}

// ---------------------------------------------------------------------------
// Kernel B: block-sparse window attention. One block per (b, head, q-window).
// 256 threads = 64 query rows x 4 key-groups of 16 keys.
// ---------------------------------------------------------------------------
__global__ __launch_bounds__(256)
void win_attn(const float* __restrict__ qg, const float* __restrict__ kg,
              const float* __restrict__ vg, const int* __restrict__ mask,
              float* __restrict__ og)
{
    const int wi = blockIdx.x;   // query window
    const int nh = blockIdx.y;
    const int b  = blockIdx.z;
    const int tid  = threadIdx.x;
    const int qrow = tid >> 2;   // 0..63
    const int kgi  = tid & 3;    // 0..3
    __shared__ float Ks[64][32];
    __shared__ float Vs[64][32];

    const size_t base = (size_t)(b * NH + nh) * NTOK * HD;

    float q[32];
    {
        const float* qp = qg + base + (size_t)(wi * 64 + qrow) * HD;
#pragma unroll
        for (int d4 = 0; d4 < 8; ++d4) {
            float4 v = *(const float4*)(qp + d4 * 4);
            q[d4 * 4 + 0] = v.x; q[d4 * 4 + 1] = v.y;
            q[d4 * 4 + 2] = v.z; q[d4 * 4 + 3] = v.w;
        }
    }

    float m = -1e30f, lsum = 0.f;
    float o[32];
#pragma unroll
    for (int d = 0; d < 32; ++d) o[d] = 0.f;

    const int* mrow = mask + (b * WINNUM + wi) * WINNUM;
    const int sr = tid >> 2;          // staging row
    const int sd = (tid & 3) * 8;     // staging dim start

    for (int wj = 0; wj < WINNUM; ++wj) {
        if (mrow[wj] == 0) continue;          // uniform per block
        __syncthreads();                      // protect LDS reuse
        {
            const float* kp = kg + base + (size_t)(wj * 64 + sr) * HD + sd;
            const float* vp = vg + base + (size_t)(wj * 64 + sr) * HD + sd;
            *(float4*)&Ks[sr][sd]     = *(const float4*)kp;
            *(float4*)&Ks[sr][sd + 4] = *(const float4*)(kp + 4);
            *(float4*)&Vs[sr][sd]     = *(const float4*)vp;
            *(float4*)&Vs[sr][sd + 4] = *(const float4*)(vp + 4);
        }
        __syncthreads();

        float sc[16];
#pragma unroll
        for (int kk = 0; kk < 16; ++kk) {
            int kidx = kgi * 16 + kk;
            float s = 0.f;
#pragma unroll
            for (int d4 = 0; d4 < 8; ++d4) {
                float4 kv = *(const float4*)&Ks[kidx][d4 * 4];
                s += q[d4 * 4 + 0] * kv.x + q[d4 * 4 + 1] * kv.y
                   + q[d4 * 4 + 2] * kv.z + q[d4 * 4 + 3] * kv.w;
            }
            sc[kk] = s;
        }
        float tmax = sc[0];
#pragma unroll
        for (int kk = 1; kk < 16; ++kk) tmax = fmaxf(tmax, sc[kk]);
        tmax = fmaxf(tmax, __shfl_xor(tmax, 1));
        tmax = fmaxf(tmax, __shfl_xor(tmax, 2));
        float newm = fmaxf(m, tmax);
        float corr = __expf(m - newm);
        m = newm;
        lsum *= corr;
#pragma unroll
        for (int d = 0; d < 32; ++d) o[d] *= corr;
        float p[16];
#pragma unroll
        for (int kk = 0; kk < 16; ++kk) { p[kk] = __expf(sc[kk] - m); lsum += p[kk]; }
#pragma unroll
        for (int kk = 0; kk < 16; ++kk) {
            int kidx = kgi * 16 + kk;
#pragma unroll
            for (int d4 = 0; d4 < 8; ++d4) {
                float4 vv = *(const float4*)&Vs[kidx][d4 * 4];
                o[d4 * 4 + 0] += p[kk] * vv.x; o[d4 * 4 + 1] += p[kk] * vv.y;
                o[d4 * 4 + 2] += p[kk] * vv.z; o[d4 * 4 + 3] += p[kk] * vv.w;
            }
        }
    }

    // cls key — always attended
    {
        const float* kp = kg + base + (size_t)LWIN * HD;
        const float* vp = vg + base + (size_t)LWIN * HD;
        float s = 0.f;
#pragma unroll
        for (int d4 = 0; d4 < 8; ++d4) {
            float4 kv = *(const float4*)(kp + d4 * 4);
            s += q[d4 * 4 + 0] * kv.x + q[d4 * 4 + 1] * kv.y
               + q[d4 * 4 + 2] * kv.z + q[d4 * 4 + 3] * kv.w;
        }
        float newm = fmaxf(m, s);
        float corr = __expf(m - newm);
        m = newm;
        lsum *= corr;
#pragma unroll
        for (int d = 0; d < 32; ++d) o[d] *= corr;
        if (kgi == 0) {
            float p = __expf(s - m);
            lsum += p;
#pragma unroll
            for (int d4 = 0; d4 < 8; ++d4) {
                float4 vv = *(const float4*)(vp + d4 * 4);
                o[d4 * 4 + 0] += p * vv.x; o[d4 * 4 + 1] += p * vv.y;
                o[d4 * 4 + 2] += p * vv.z; o[d4 * 4 + 3] += p * vv.w;
            }
        }
    }

    // reduce partials across the 4 key-group lanes
    lsum += __shfl_xor(lsum, 1);
    lsum += __shfl_xor(lsum, 2);
#pragma unroll
    for (int d = 0; d < 32; ++d) {
        o[d] += __shfl_xor(o[d], 1);
        o[d] += __shfl_xor(o[d], 2);
    }
    if (kgi == 0) {
        float inv = 1.f / lsum;
        float* op = og + base + (size_t)(wi * 64 + qrow) * HD;
#pragma unroll
        for (int d4 = 0; d4 < 8; ++d4) {
            *(float4*)(op + d4 * 4) = make_float4(o[d4 * 4 + 0] * inv, o[d4 * 4 + 1] * inv,
                                                  o[d4 * 4 + 2] * inv, o[d4 * 4 + 3] * inv);
        }
    }
}

// ---------------------------------------------------------------------------
// Kernel C: cls-token query attends to all 3137 keys. One wave per (b, head).
// ---------------------------------------------------------------------------
__global__ __launch_bounds__(64)
void cls_attn(const float* __restrict__ qg, const float* __restrict__ kg,
              const float* __restrict__ vg, float* __restrict__ og)
{
    const int bh = blockIdx.x;
    const int lane = threadIdx.x;
    const size_t base = (size_t)bh * NTOK * HD;

    float q[32];
    {
        const float* qp = qg + base + (size_t)LWIN * HD;
#pragma unroll
        for (int d4 = 0; d4 < 8; ++d4) {
            float4 v = *(const float4*)(qp + d4 * 4);
            q[d4 * 4 + 0] = v.x; q[d4 * 4 + 1] = v.y;
            q[d4 * 4 + 2] = v.z; q[d4 * 4 + 3] = v.w;
        }
    }
    float m = -1e30f, l = 0.f;
    float o[32];
#pragma unroll
    for (int d = 0; d < 32; ++d) o[d] = 0.f;

    for (int k = lane; k < NTOK; k += 64) {
        const float* kp = kg + base + (size_t)k * HD;
        float s = 0.f;
#pragma unroll
        for (int d4 = 0; d4 < 8; ++d4) {
            float4 kv = *(const float4*)(kp + d4 * 4);
            s += q[d4 * 4 + 0] * kv.x + q[d4 * 4 + 1] * kv.y
               + q[d4 * 4 + 2] * kv.z + q[d4 * 4 + 3] * kv.w;
        }
        float newm = fmaxf(m, s);
        float corr = __expf(m - newm);
        float p = __expf(s - newm);
        m = newm;
        l = l * corr + p;
        const float* vp = vg + base + (size_t)k * HD;
#pragma unroll
        for (int d4 = 0; d4 < 8; ++d4) {
            float4 vv = *(const float4*)(vp + d4 * 4);
            o[d4 * 4 + 0] = o[d4 * 4 + 0] * corr + p * vv.x;
            o[d4 * 4 + 1] = o[d4 * 4 + 1] * corr + p * vv.y;
            o[d4 * 4 + 2] = o[d4 * 4 + 2] * corr + p * vv.z;
            o[d4 * 4 + 3] = o[d4 * 4 + 3] * corr + p * vv.w;
        }
    }
    // merge across 64 lanes
#pragma unroll
    for (int off = 1; off < 64; off <<= 1) {
        float m2 = __shfl_xor(m, off);
        float l2 = __shfl_xor(l, off);
        float newm = fmaxf(m, m2);
        float ca = __expf(m - newm), cb = __expf(m2 - newm);
        l = l * ca + l2 * cb;
#pragma unroll
        for (int d = 0; d < 32; ++d) {
            float od2 = __shfl_xor(o[d], off);
            o[d] = o[d] * ca + od2 * cb;
        }
        m = newm;
    }
    if (lane == 0) {
        float inv = 1.f / l;
        float* op = og + base + (size_t)LWIN * HD;
#pragma unroll
        for (int d4 = 0; d4 < 8; ++d4) {
            *(float4*)(op + d4 * 4) = make_float4(o[d4 * 4 + 0] * inv, o[d4 * 4 + 1] * inv,
                                                  o[d4 * 4 + 2] * inv, o[d4 * 4 + 3] * inv);
        }
    }
}

// ---------------------------------------------------------------------------
// Kernel D1: t = un-windowed attn output + depthwise 3x3 lepe(v) + lepe_b.
// cls rows: t = attn output only. t row-major (12548, 256).
// ---------------------------------------------------------------------------
__global__ __launch_bounds__(256)
void gather_lepe(const float* __restrict__ og, const float* __restrict__ vg,
                 const float* __restrict__ lk, const float* __restrict__ lb,
                 float* __restrict__ t)
{
    const int pix = blockIdx.x;
    const int c = threadIdx.x;
    const int nh = c >> 5, d = c & 31;
    if (pix >= NPIX) {
        int b = pix - NPIX;
        size_t src = ((size_t)(b * NH + nh) * NTOK + LWIN) * HD + d;
        t[(size_t)pix * 256 + c] = og[src];
        return;
    }
    int b = pix / LWIN, p = pix % LWIN;
    int h = p / 56, w = p % 56;
    int tok = ((h >> 3) * 7 + (w >> 3)) * 64 + ((h & 7) << 3) + (w & 7);
    size_t base = (size_t)(b * NH + nh) * NTOK * HD + d;
    float acc = og[base + (size_t)tok * HD];
    float conv = lb[c];
#pragma unroll
    for (int dh = -1; dh <= 1; ++dh) {
        int hh = h + dh;
        if (hh < 0 || hh >= 56) continue;
#pragma unroll
        for (int dw = -1; dw <= 1; ++dw) {
            int ww2 = w + dw;
            if (ww2 < 0 || ww2 >= 56) continue;
            int tok2 = ((hh >> 3) * 7 + (ww2 >> 3)) * 64 + ((hh & 7) << 3) + (ww2 & 7);
            conv += vg[base + (size_t)tok2 * HD] * lk[((dh + 1) * 3 + (dw + 1)) * 256 + c];
        }
    }
    t[(size_t)pix * 256 + c] = acc + conv;
}

// ---------------------------------------------------------------------------
// Kernel D2: out = t @ Wo + bo -> x_out (spatial) then cls_out.
// ---------------------------------------------------------------------------
__global__ __launch_bounds__(256)
void out_gemm(const float* __restrict__ t, const float* __restrict__ Wo,
              const float* __restrict__ bo, float* __restrict__ out)
{
    __shared__ float As[64][16];
    __shared__ float Bs[16][64];
    const int m0 = blockIdx.y * 64;
    const int n0 = blockIdx.x * 64;
    const int tid = threadIdx.x;
    const int ty = tid >> 4, tx = tid & 15;
    const int lr = tid >> 2, lk = (tid & 3) * 4;
    const int lkb = tid >> 4, lcb = (tid & 15) * 4;
    float acc[4][4] = {};

    for (int k0 = 0; k0 < 256; k0 += 16) {
        int m = m0 + lr;
        float4 av = make_float4(0.f, 0.f, 0.f, 0.f);
        if (m < MROWS) av = *(const float4*)(t + (size_t)m * 256 + k0 + lk);
        *(float4*)&As[lr][lk] = av;
        *(float4*)&Bs[lkb][lcb] = *(const float4*)(Wo + (size_t)(k0 + lkb) * 256 + n0 + lcb);
        __syncthreads();
#pragma unroll
        for (int kk = 0; kk < 16; ++kk) {
            float a[4], bb[4];
#pragma unroll
            for (int i = 0; i < 4; ++i) a[i] = As[ty * 4 + i][kk];
#pragma unroll
            for (int j = 0; j < 4; ++j) bb[j] = Bs[kk][tx * 4 + j];
#pragma unroll
            for (int i = 0; i < 4; ++i)
#pragma unroll
                for (int j = 0; j < 4; ++j) acc[i][j] += a[i] * bb[j];
        }
        __syncthreads();
    }
#pragma unroll
    for (int i = 0; i < 4; ++i) {
        int m = m0 + ty * 4 + i;
        if (m >= MROWS) continue;
        float* dst = (m < NPIX) ? (out + (size_t)m * 256)
                                : (out + (size_t)NPIX * 256 + (size_t)(m - NPIX) * 256);
#pragma unroll
        for (int j = 0; j < 4; ++j) {
            int n = n0 + tx * 4 + j;
            dst[n] = acc[i][j] + bo[n];
        }
    }
}

// ---------------------------------------------------------------------------
extern "C" void kernel_launch(void* const* d_in, const int* in_sizes, int n_in,
                              void* d_out, int out_size, void* d_ws, size_t ws_size,
                              hipStream_t stream)
{
    const float* x    = (const float*)d_in[0];
    const float* cls  = (const float*)d_in[1];
    const int*   mask = (const int*)d_in[2];
    const float* Wqkv = (const float*)d_in[5];
    const float* bqkv = (const float*)d_in[6];
    const float* Wo   = (const float*)d_in[7];
    const float* bo   = (const float*)d_in[8];
    const float* lk   = (const float*)d_in[9];
    const float* lb   = (const float*)d_in[10];
    float* out = (float*)d_out;

    const size_t BUF = (size_t)B_ * NH * NTOK * HD;   // 3,212,288 floats
    float* qg = (float*)d_ws;
    float* kg = qg + BUF;
    float* vg = kg + BUF;
    float* og = vg + BUF;
    float* t  = qg;   // reuse q buffer after attention kernels are done with it

    qkv_gemm<<<dim3(12, 197), 256, 0, stream>>>(x, cls, Wqkv, bqkv, qg, kg, vg);
    win_attn<<<dim3(49, NH, B_), 256, 0, stream>>>(qg, kg, vg, mask, og);
    cls_attn<<<dim3(32), 64, 0, stream>>>(qg, kg, vg, og);
    gather_lepe<<<dim3(MROWS), 256, 0, stream>>>(og, vg, lk, lb, t);
    out_gemm<<<dim3(4, 197), 256, 0, stream>>>(t, Wo, bo, out);
}

// Round 2
// 289.129 us; speedup vs baseline: 3.5783x; 3.5783x over previous
//
#include <hip/hip_runtime.h>
#include <math.h>

#define B_      4
#define C_      256
#define NH      8
#define HD      32
#define WINNUM  49
#define LWIN    3136
#define NTOK    3137
#define NPIX    12544     // B * 56 * 56
#define MROWS   12548     // NPIX + 4 cls rows
#define SCALE   0.0625f   // 256^-0.5

using short8 = __attribute__((ext_vector_type(8))) short;
using f32x4  = __attribute__((ext_vector_type(4))) float;

__device__ __forceinline__ short f2bf(float f) {
    unsigned u = __builtin_bit_cast(unsigned, f);
    unsigned r = (u + 0x7fffu + ((u >> 16) & 1u)) >> 16;
    return (short)r;
}

// ---------------------------------------------------------------------------
// Kernel A: qkv = [x; cls] @ Wqkv + bqkv, scattered to window-ordered layout
// (B, Nh, 3137, 32). q pre-scaled by SCALE.
// ---------------------------------------------------------------------------
__global__ __launch_bounds__(256)
void qkv_gemm(const float* __restrict__ x, const float* __restrict__ cls,
              const float* __restrict__ Wqkv, const float* __restrict__ bqkv,
              float* __restrict__ qg, float* __restrict__ kg, float* __restrict__ vg)
{
    __shared__ float As[64][16];
    __shared__ float Bs[16][64];
    const int m0 = blockIdx.y * 64;
    const int n0 = blockIdx.x * 64;
    const int tid = threadIdx.x;
    const int ty = tid >> 4, tx = tid & 15;
    const int lr = tid >> 2, lk = (tid & 3) * 4;
    const int lkb = tid >> 4, lcb = (tid & 15) * 4;
    float acc[4][4] = {};

    for (int k0 = 0; k0 < 256; k0 += 16) {
        int m = m0 + lr;
        float4 av = make_float4(0.f, 0.f, 0.f, 0.f);
        if (m < MROWS) {
            const float* src = (m < NPIX) ? (x + (size_t)m * 256)
                                          : (cls + (size_t)(m - NPIX) * 256);
            av = *(const float4*)(src + k0 + lk);
        }
        *(float4*)&As[lr][lk] = av;
        *(float4*)&Bs[lkb][lcb] = *(const float4*)(Wqkv + (size_t)(k0 + lkb) * 768 + n0 + lcb);
        __syncthreads();
#pragma unroll
        for (int kk = 0; kk < 16; ++kk) {
            float a[4], bb[4];
#pragma unroll
            for (int i = 0; i < 4; ++i) a[i] = As[ty * 4 + i][kk];
#pragma unroll
            for (int j = 0; j < 4; ++j) bb[j] = Bs[kk][tx * 4 + j];
#pragma unroll
            for (int i = 0; i < 4; ++i)
#pragma unroll
                for (int j = 0; j < 4; ++j) acc[i][j] += a[i] * bb[j];
        }
        __syncthreads();
    }

#pragma unroll
    for (int i = 0; i < 4; ++i) {
        int m = m0 + ty * 4 + i;
        if (m >= MROWS) continue;
        int b, tok;
        if (m < NPIX) {
            b = m / LWIN;
            int p = m % LWIN;
            int h = p / 56, w = p % 56;
            tok = ((h >> 3) * 7 + (w >> 3)) * 64 + ((h & 7) << 3) + (w & 7);
        } else {
            b = m - NPIX; tok = LWIN;
        }
#pragma unroll
        for (int j = 0; j < 4; ++j) {
            int n = n0 + tx * 4 + j;
            float val = acc[i][j] + bqkv[n];
            int part = n >> 8;
            int c = n & 255;
            int nh = c >> 5, d = c & 31;
            size_t dst = ((size_t)(b * NH + nh) * NTOK + tok) * HD + d;
            if (part == 0)       qg[dst] = val * SCALE;
            else if (part == 1)  kg[dst] = val;
            else                 vg[dst] = val;
        }
    }
}

// ---------------------------------------------------------------------------
// Kernel B: block-sparse window attention, bf16 MFMA version.
// One block (4 waves) per (b, head, q-window). Wave w owns query rows
// 16w..16w+15. Computes S^T = mfma(K, Q) so each lane's column is one query:
// softmax row-reduce = 2 shuffles (xor 16, 32). P round-trips LDS to become
// the B-operand of O^T = mfma(V^T, P^T).
// LDS strides padded (K: 40, Vt/P: 72 shorts) for uniform bank distribution.
// ---------------------------------------------------------------------------
__global__ __launch_bounds__(256)
void win_attn(const float* __restrict__ qg, const float* __restrict__ kg,
              const float* __restrict__ vg, const int* __restrict__ mask,
              float* __restrict__ og)
{
    const int wi = blockIdx.x;   // query window
    const int nh = blockIdx.y;
    const int b  = blockIdx.z;
    const int tid = threadIdx.x;

    __shared__ short Klds[2][64 * 40];   // [key][dim], stride 40 shorts (80B)
    __shared__ short Vt[2][32 * 72];     // [dim][key], stride 72 shorts (144B)
    __shared__ short Plds[4][16 * 72];   // per wave: [q][key], stride 72

    const size_t base = (size_t)(b * NH + nh) * NTOK * HD;

    // staging indices
    const int krow = tid >> 2, kc0 = (tid & 3) * 8;       // K: row, 8 dims
    const int vk0 = (tid & 31) * 2, vd0 = (tid >> 5) * 4; // V: 2 keys, 4 dims

    // compute indices
    const int lane = tid & 63, wv = tid >> 6;
    const int g = lane >> 4, qi = lane & 15;
    const int qrow = wi * 64 + wv * 16 + qi;

    // Q fragment: fp32 copy (for cls) + bf16 frag (MFMA B operand)
    float qf[8];
    short8 aq;
    {
        const float* qp = qg + base + (size_t)qrow * HD + g * 8;
        float4 a = *(const float4*)qp, c = *(const float4*)(qp + 4);
        qf[0]=a.x; qf[1]=a.y; qf[2]=a.z; qf[3]=a.w;
        qf[4]=c.x; qf[5]=c.y; qf[6]=c.z; qf[7]=c.w;
#pragma unroll
        for (int j = 0; j < 8; ++j) aq[j] = f2bf(qf[j]);
    }
    // cls K/V preload (fp32)
    float kcls[8], vcls[2][4];
    {
        const float* kcb = kg + base + (size_t)LWIN * HD;
        const float* vcb = vg + base + (size_t)LWIN * HD;
#pragma unroll
        for (int j = 0; j < 8; ++j) kcls[j] = kcb[g * 8 + j];
#pragma unroll
        for (int h = 0; h < 2; ++h)
#pragma unroll
            for (int r = 0; r < 4; ++r) vcls[h][r] = vcb[h * 16 + g * 4 + r];
    }

    float m = -1e30f, l = 0.f;
    f32x4 acc[2] = {{0.f,0.f,0.f,0.f},{0.f,0.f,0.f,0.f}};

    const int* mrow = mask + (b * WINNUM + wi) * WINNUM;
    int buf = 0;

    for (int wj = 0; wj < WINNUM; ++wj) {
        if (mrow[wj] == 0) continue;
        // ---- stage K (row-major) and V (transposed) as bf16 ----
        {
            const float* kp = kg + base + (size_t)(wj * 64 + krow) * HD + kc0;
            float4 a = *(const float4*)kp, c = *(const float4*)(kp + 4);
            short8 kv;
            kv[0]=f2bf(a.x); kv[1]=f2bf(a.y); kv[2]=f2bf(a.z); kv[3]=f2bf(a.w);
            kv[4]=f2bf(c.x); kv[5]=f2bf(c.y); kv[6]=f2bf(c.z); kv[7]=f2bf(c.w);
            *(short8*)&Klds[buf][krow * 40 + kc0] = kv;

            const float* vp0 = vg + base + (size_t)(wj * 64 + vk0) * HD + vd0;
            float4 v0 = *(const float4*)vp0;
            float4 v1 = *(const float4*)(vp0 + HD);
            float lo[4] = {v0.x, v0.y, v0.z, v0.w};
            float hi[4] = {v1.x, v1.y, v1.z, v1.w};
#pragma unroll
            for (int j = 0; j < 4; ++j) {
                unsigned pk = (unsigned)(unsigned short)f2bf(lo[j])
                            | ((unsigned)(unsigned short)f2bf(hi[j]) << 16);
                *(unsigned*)&Vt[buf][(vd0 + j) * 72 + vk0] = pk;
            }
        }
        __syncthreads();

        // ---- S^T tiles: st[t] covers keys 16t..16t+15 for query qi ----
        f32x4 st[4];
#pragma unroll
        for (int t = 0; t < 4; ++t) {
            short8 ak = *(const short8*)&Klds[buf][(t * 16 + qi) * 40 + g * 8];
            st[t] = __builtin_amdgcn_mfma_f32_16x16x32_bf16(
                        ak, aq, (f32x4){0.f,0.f,0.f,0.f}, 0, 0, 0);
        }
        // ---- online softmax (per query column qi) ----
        float tmax = st[0][0];
#pragma unroll
        for (int t = 0; t < 4; ++t)
#pragma unroll
            for (int r = 0; r < 4; ++r) tmax = fmaxf(tmax, st[t][r]);
        tmax = fmaxf(tmax, __shfl_xor(tmax, 16));
        tmax = fmaxf(tmax, __shfl_xor(tmax, 32));
        float mnew = fmaxf(m, tmax);
        float corr = __expf(m - mnew);
        m = mnew;
        float p[4][4];
        float ls = 0.f;
#pragma unroll
        for (int t = 0; t < 4; ++t)
#pragma unroll
            for (int r = 0; r < 4; ++r) { p[t][r] = __expf(st[t][r] - m); ls += p[t][r]; }
        ls += __shfl_xor(ls, 16);
        ls += __shfl_xor(ls, 32);
        l = l * corr + ls;
#pragma unroll
        for (int h = 0; h < 2; ++h)
#pragma unroll
            for (int r = 0; r < 4; ++r) acc[h][r] *= corr;
        // ---- P -> LDS (bf16, packed pairs along key) ----
        {
            short* pw = &Plds[wv][qi * 72];
#pragma unroll
            for (int t = 0; t < 4; ++t)
#pragma unroll
                for (int r2 = 0; r2 < 2; ++r2) {
                    unsigned pk = (unsigned)(unsigned short)f2bf(p[t][2 * r2])
                                | ((unsigned)(unsigned short)f2bf(p[t][2 * r2 + 1]) << 16);
                    *(unsigned*)&pw[t * 16 + g * 4 + r2 * 2] = pk;
                }
        }
        // ---- O^T += V^T . P^T  (2 d-halves x 2 K-steps) ----
#pragma unroll
        for (int s = 0; s < 2; ++s) {
            short8 bp = *(const short8*)&Plds[wv][qi * 72 + s * 32 + g * 8];
#pragma unroll
            for (int h = 0; h < 2; ++h) {
                short8 av = *(const short8*)&Vt[buf][(h * 16 + qi) * 72 + s * 32 + g * 8];
                acc[h] = __builtin_amdgcn_mfma_f32_16x16x32_bf16(av, bp, acc[h], 0, 0, 0);
            }
        }
        buf ^= 1;
    }

    // ---- cls key (fp32 scalar path) ----
    {
        float s = 0.f;
#pragma unroll
        for (int j = 0; j < 8; ++j) s += qf[j] * kcls[j];
        s += __shfl_xor(s, 16);
        s += __shfl_xor(s, 32);
        float mnew = fmaxf(m, s);
        float corr = __expf(m - mnew);
        m = mnew;
        float pc = __expf(s - mnew);
        l = l * corr + pc;
#pragma unroll
        for (int h = 0; h < 2; ++h)
#pragma unroll
            for (int r = 0; r < 4; ++r) acc[h][r] = acc[h][r] * corr + pc * vcls[h][r];
    }

    // ---- normalize + write (O^T: lane holds d = 16h+4g+r for query qi) ----
    {
        float inv = 1.f / l;
        float* op = og + base + (size_t)qrow * HD;
#pragma unroll
        for (int h = 0; h < 2; ++h)
#pragma unroll
            for (int r = 0; r < 4; ++r) op[h * 16 + g * 4 + r] = acc[h][r] * inv;
    }
}

// ---------------------------------------------------------------------------
// Kernel C: cls-token query attends to all 3137 keys. One wave per (b, head).
// ---------------------------------------------------------------------------
__global__ __launch_bounds__(64)
void cls_attn(const float* __restrict__ qg, const float* __restrict__ kg,
              const float* __restrict__ vg, float* __restrict__ og)
{
    const int bh = blockIdx.x;
    const int lane = threadIdx.x;
    const size_t base = (size_t)bh * NTOK * HD;

    float q[32];
    {
        const float* qp = qg + base + (size_t)LWIN * HD;
#pragma unroll
        for (int d4 = 0; d4 < 8; ++d4) {
            float4 v = *(const float4*)(qp + d4 * 4);
            q[d4 * 4 + 0] = v.x; q[d4 * 4 + 1] = v.y;
            q[d4 * 4 + 2] = v.z; q[d4 * 4 + 3] = v.w;
        }
    }
    float m = -1e30f, l = 0.f;
    float o[32];
#pragma unroll
    for (int d = 0; d < 32; ++d) o[d] = 0.f;

    for (int k = lane; k < NTOK; k += 64) {
        const float* kp = kg + base + (size_t)k * HD;
        float s = 0.f;
#pragma unroll
        for (int d4 = 0; d4 < 8; ++d4) {
            float4 kv = *(const float4*)(kp + d4 * 4);
            s += q[d4 * 4 + 0] * kv.x + q[d4 * 4 + 1] * kv.y
               + q[d4 * 4 + 2] * kv.z + q[d4 * 4 + 3] * kv.w;
        }
        float newm = fmaxf(m, s);
        float corr = __expf(m - newm);
        float p = __expf(s - newm);
        m = newm;
        l = l * corr + p;
        const float* vp = vg + base + (size_t)k * HD;
#pragma unroll
        for (int d4 = 0; d4 < 8; ++d4) {
            float4 vv = *(const float4*)(vp + d4 * 4);
            o[d4 * 4 + 0] = o[d4 * 4 + 0] * corr + p * vv.x;
            o[d4 * 4 + 1] = o[d4 * 4 + 1] * corr + p * vv.y;
            o[d4 * 4 + 2] = o[d4 * 4 + 2] * corr + p * vv.z;
            o[d4 * 4 + 3] = o[d4 * 4 + 3] * corr + p * vv.w;
        }
    }
#pragma unroll
    for (int off = 1; off < 64; off <<= 1) {
        float m2 = __shfl_xor(m, off);
        float l2 = __shfl_xor(l, off);
        float newm = fmaxf(m, m2);
        float ca = __expf(m - newm), cb = __expf(m2 - newm);
        l = l * ca + l2 * cb;
#pragma unroll
        for (int d = 0; d < 32; ++d) {
            float od2 = __shfl_xor(o[d], off);
            o[d] = o[d] * ca + od2 * cb;
        }
        m = newm;
    }
    if (lane == 0) {
        float inv = 1.f / l;
        float* op = og + base + (size_t)LWIN * HD;
#pragma unroll
        for (int d4 = 0; d4 < 8; ++d4) {
            *(float4*)(op + d4 * 4) = make_float4(o[d4 * 4 + 0] * inv, o[d4 * 4 + 1] * inv,
                                                  o[d4 * 4 + 2] * inv, o[d4 * 4 + 3] * inv);
        }
    }
}

// ---------------------------------------------------------------------------
// Kernel D1: t = un-windowed attn output + depthwise 3x3 lepe(v) + lepe_b.
// ---------------------------------------------------------------------------
__global__ __launch_bounds__(256)
void gather_lepe(const float* __restrict__ og, const float* __restrict__ vg,
                 const float* __restrict__ lk, const float* __restrict__ lb,
                 float* __restrict__ t)
{
    const int pix = blockIdx.x;
    const int c = threadIdx.x;
    const int nh = c >> 5, d = c & 31;
    if (pix >= NPIX) {
        int b = pix - NPIX;
        size_t src = ((size_t)(b * NH + nh) * NTOK + LWIN) * HD + d;
        t[(size_t)pix * 256 + c] = og[src];
        return;
    }
    int b = pix / LWIN, p = pix % LWIN;
    int h = p / 56, w = p % 56;
    int tok = ((h >> 3) * 7 + (w >> 3)) * 64 + ((h & 7) << 3) + (w & 7);
    size_t base = (size_t)(b * NH + nh) * NTOK * HD + d;
    float acc = og[base + (size_t)tok * HD];
    float conv = lb[c];
#pragma unroll
    for (int dh = -1; dh <= 1; ++dh) {
        int hh = h + dh;
        if (hh < 0 || hh >= 56) continue;
#pragma unroll
        for (int dw = -1; dw <= 1; ++dw) {
            int ww2 = w + dw;
            if (ww2 < 0 || ww2 >= 56) continue;
            int tok2 = ((hh >> 3) * 7 + (ww2 >> 3)) * 64 + ((hh & 7) << 3) + (ww2 & 7);
            conv += vg[base + (size_t)tok2 * HD] * lk[((dh + 1) * 3 + (dw + 1)) * 256 + c];
        }
    }
    t[(size_t)pix * 256 + c] = acc + conv;
}

// ---------------------------------------------------------------------------
// Kernel D2: out = t @ Wo + bo -> x_out (spatial) then cls_out.
// ---------------------------------------------------------------------------
__global__ __launch_bounds__(256)
void out_gemm(const float* __restrict__ t, const float* __restrict__ Wo,
              const float* __restrict__ bo, float* __restrict__ out)
{
    __shared__ float As[64][16];
    __shared__ float Bs[16][64];
    const int m0 = blockIdx.y * 64;
    const int n0 = blockIdx.x * 64;
    const int tid = threadIdx.x;
    const int ty = tid >> 4, tx = tid & 15;
    const int lr = tid >> 2, lk = (tid & 3) * 4;
    const int lkb = tid >> 4, lcb = (tid & 15) * 4;
    float acc[4][4] = {};

    for (int k0 = 0; k0 < 256; k0 += 16) {
        int m = m0 + lr;
        float4 av = make_float4(0.f, 0.f, 0.f, 0.f);
        if (m < MROWS) av = *(const float4*)(t + (size_t)m * 256 + k0 + lk);
        *(float4*)&As[lr][lk] = av;
        *(float4*)&Bs[lkb][lcb] = *(const float4*)(Wo + (size_t)(k0 + lkb) * 256 + n0 + lcb);
        __syncthreads();
#pragma unroll
        for (int kk = 0; kk < 16; ++kk) {
            float a[4], bb[4];
#pragma unroll
            for (int i = 0; i < 4; ++i) a[i] = As[ty * 4 + i][kk];
#pragma unroll
            for (int j = 0; j < 4; ++j) bb[j] = Bs[kk][tx * 4 + j];
#pragma unroll
            for (int i = 0; i < 4; ++i)
#pragma unroll
                for (int j = 0; j < 4; ++j) acc[i][j] += a[i] * bb[j];
        }
        __syncthreads();
    }
#pragma unroll
    for (int i = 0; i < 4; ++i) {
        int m = m0 + ty * 4 + i;
        if (m >= MROWS) continue;
        float* dst = (m < NPIX) ? (out + (size_t)m * 256)
                                : (out + (size_t)NPIX * 256 + (size_t)(m - NPIX) * 256);
#pragma unroll
        for (int j = 0; j < 4; ++j) {
            int n = n0 + tx * 4 + j;
            dst[n] = acc[i][j] + bo[n];
        }
    }
}

// ---------------------------------------------------------------------------
extern "C" void kernel_launch(void* const* d_in, const int* in_sizes, int n_in,
                              void* d_out, int out_size, void* d_ws, size_t ws_size,
                              hipStream_t stream)
{
    const float* x    = (const float*)d_in[0];
    const float* cls  = (const float*)d_in[1];
    const int*   mask = (const int*)d_in[2];
    const float* Wqkv = (const float*)d_in[5];
    const float* bqkv = (const float*)d_in[6];
    const float* Wo   = (const float*)d_in[7];
    const float* bo   = (const float*)d_in[8];
    const float* lk   = (const float*)d_in[9];
    const float* lb   = (const float*)d_in[10];
    float* out = (float*)d_out;

    const size_t BUF = (size_t)B_ * NH * NTOK * HD;
    float* qg = (float*)d_ws;
    float* kg = qg + BUF;
    float* vg = kg + BUF;
    float* og = vg + BUF;
    float* t  = qg;   // reuse q buffer after attention

    qkv_gemm<<<dim3(12, 197), 256, 0, stream>>>(x, cls, Wqkv, bqkv, qg, kg, vg);
    win_attn<<<dim3(49, NH, B_), 256, 0, stream>>>(qg, kg, vg, mask, og);
    cls_attn<<<dim3(32), 64, 0, stream>>>(qg, kg, vg, og);
    gather_lepe<<<dim3(MROWS), 256, 0, stream>>>(og, vg, lk, lb, t);
    out_gemm<<<dim3(4, 197), 256, 0, stream>>>(t, Wo, bo, out);
}

// Round 3
// 197.269 us; speedup vs baseline: 5.2445x; 1.4657x over previous
//
#include <hip/hip_runtime.h>
#include <math.h>

#define B_      4
#define NH      8
#define HD      32
#define WINNUM  49
#define LWIN    3136
#define NTOK    3137
#define NPIX    12544     // B * 56 * 56
#define MROWS   12548     // NPIX + 4 cls rows
// 256^-0.5 * log2(e): scores land in exp2 domain
#define SCALE_L2E 0.09016844005556021f

typedef _Float16 half_t;
using half8 = __attribute__((ext_vector_type(8))) half_t;
using half4 = __attribute__((ext_vector_type(4))) half_t;
using f32x4 = __attribute__((ext_vector_type(4))) float;

__device__ __forceinline__ unsigned short h16(float f) {
    half_t h = (half_t)f;
    return __builtin_bit_cast(unsigned short, h);
}

// ---------------------------------------------------------------------------
// prep: fp32 -> fp16 conversions. xh = [x; cls] (12548,256); Wqkvt (768,256)
// and Wot (256,256) transposed (row = output col, k contiguous).
// ---------------------------------------------------------------------------
__global__ __launch_bounds__(256)
void prep(const float* __restrict__ x, const float* __restrict__ cls,
          const float* __restrict__ Wqkv, const float* __restrict__ Wo,
          half_t* __restrict__ xh, half_t* __restrict__ Wqkvt, half_t* __restrict__ Wot)
{
    const int idx = blockIdx.x * 256 + threadIdx.x;
    const int stride = gridDim.x * 256;
    for (int i = idx; i < MROWS * 256; i += stride) {
        int row = i >> 8, c = i & 255;
        float v = (row < NPIX) ? x[i] : cls[(row - NPIX) * 256 + c];
        xh[i] = (half_t)v;
    }
    for (int i = idx; i < 768 * 256; i += stride) {
        int n = i >> 8, k = i & 255;
        Wqkvt[i] = (half_t)Wqkv[k * 768 + n];
    }
    for (int i = idx; i < 256 * 256; i += stride) {
        int n = i >> 8, k = i & 255;
        Wot[i] = (half_t)Wo[k * 256 + n];
    }
}

// ---------------------------------------------------------------------------
// qkv_gemm: C = xh @ Wqkv + bqkv via fp16 MFMA, 128x128 tile, 4 waves (2x2).
// Epilogue scatters q -> qh (scaled), k -> kh windows [49][64][40] + khcls,
// v -> vplain + vh windows transposed [49][32][72].
// ---------------------------------------------------------------------------
__global__ __launch_bounds__(256)
void qkv_gemm(const half_t* __restrict__ xh, const half_t* __restrict__ Bt,
              const float* __restrict__ bqkv,
              half_t* __restrict__ qh, half_t* __restrict__ kh,
              half_t* __restrict__ khcls, half_t* __restrict__ vh,
              half_t* __restrict__ vplain)
{
    __shared__ __align__(16) short As[2][128 * 40];
    __shared__ __align__(16) short Bs[2][128 * 40];
    const int m0 = blockIdx.y * 128, n0 = blockIdx.x * 128;
    const int tid = threadIdx.x;
    const int lane = tid & 63, wv = tid >> 6;
    const int wm = wv >> 1, wn = wv & 1;
    const int qi = lane & 15, g = lane >> 4;
    f32x4 acc[4][4] = {};

    auto stage = [&](int bu, int k0) {
#pragma unroll
        for (int i = 0; i < 2; ++i) {
            int ch = tid + 256 * i;
            int row = ch >> 2, kc = (ch & 3) * 8;
            int m = m0 + row;
            int4 va = (m < MROWS) ? *(const int4*)(xh + (size_t)m * 256 + k0 + kc)
                                  : make_int4(0, 0, 0, 0);
            *(int4*)&As[bu][row * 40 + kc] = va;
            int4 vb = *(const int4*)(Bt + (size_t)(n0 + row) * 256 + k0 + kc);
            *(int4*)&Bs[bu][row * 40 + kc] = vb;
        }
    };

    stage(0, 0);
    int buf = 0;
    for (int s = 0; s < 8; ++s) {
        __syncthreads();
        if (s < 7) stage(buf ^ 1, (s + 1) * 32);
        half8 af[4], bf[4];
#pragma unroll
        for (int f = 0; f < 4; ++f) {
            af[f] = *(const half8*)&As[buf][(wm * 64 + f * 16 + qi) * 40 + g * 8];
            bf[f] = *(const half8*)&Bs[buf][(wn * 64 + f * 16 + qi) * 40 + g * 8];
        }
#pragma unroll
        for (int fm = 0; fm < 4; ++fm)
#pragma unroll
            for (int fn = 0; fn < 4; ++fn)
                acc[fm][fn] = __builtin_amdgcn_mfma_f32_16x16x32_f16(af[fm], bf[fn], acc[fm][fn], 0, 0, 0);
        buf ^= 1;
    }

    const int part = n0 >> 8;   // uniform: 128-tiles don't straddle 256-boundaries
    int nhv[4], dv[4];
    float bq[4];
#pragma unroll
    for (int fn = 0; fn < 4; ++fn) {
        int n = n0 + wn * 64 + fn * 16 + qi;
        bq[fn] = bqkv[n];
        int c = n & 255;
        nhv[fn] = c >> 5; dv[fn] = c & 31;
    }
#pragma unroll
    for (int fm = 0; fm < 4; ++fm) {
#pragma unroll
        for (int r = 0; r < 4; ++r) {
            int m = m0 + wm * 64 + fm * 16 + g * 4 + r;
            if (m >= MROWS) continue;
            int b, tok;
            if (m < NPIX) {
                b = m / LWIN;
                int p = m - b * LWIN;
                int hh = p / 56, ww = p - hh * 56;
                tok = ((hh >> 3) * 7 + (ww >> 3)) * 64 + ((hh & 7) << 3) + (ww & 7);
            } else { b = m - NPIX; tok = LWIN; }
#pragma unroll
            for (int fn = 0; fn < 4; ++fn) {
                float val = acc[fm][fn][r] + bq[fn];
                size_t bh = (size_t)(b * NH + nhv[fn]);
                int d = dv[fn];
                if (part == 0) {
                    qh[(bh * NTOK + tok) * 32 + d] = (half_t)(val * SCALE_L2E);
                } else if (part == 1) {
                    if (tok < LWIN) kh[(bh * WINNUM + (tok >> 6)) * 2560 + (tok & 63) * 40 + d] = (half_t)val;
                    else            khcls[bh * 32 + d] = (half_t)val;
                } else {
                    vplain[(bh * NTOK + tok) * 32 + d] = (half_t)val;
                    if (tok < LWIN) vh[(bh * WINNUM + (tok >> 6)) * 2304 + d * 72 + (tok & 63)] = (half_t)val;
                }
            }
        }
    }
}

// ---------------------------------------------------------------------------
// win_attn: fp16 MFMA block-sparse window attention. Staging = pure linear
// 16B copies from pre-padded fp16 window layouts. One barrier per window.
// Writes O directly to t[pix][256] (fp16).
// ---------------------------------------------------------------------------
__global__ __launch_bounds__(256)
void win_attn(const half_t* __restrict__ qh, const half_t* __restrict__ kh,
              const half_t* __restrict__ khcls, const half_t* __restrict__ vh,
              const half_t* __restrict__ vplain, const int* __restrict__ mask,
              half_t* __restrict__ tg)
{
    const int wi = blockIdx.x, nh = blockIdx.y, b = blockIdx.z;
    const int tid = threadIdx.x;
    __shared__ __align__(16) short Klds[2][2560];   // [64][40]
    __shared__ __align__(16) short Vt[2][2304];     // [32][72]
    __shared__ __align__(16) short Plds[4][16 * 72];
    const int lane = tid & 63, wv = tid >> 6;
    const int g = lane >> 4, qi = lane & 15;
    const int bh = b * NH + nh;
    const int qrow = wi * 64 + wv * 16 + qi;

    half8 aq = *(const half8*)(qh + ((size_t)bh * NTOK + qrow) * 32 + g * 8);
    float qf[8];
#pragma unroll
    for (int j = 0; j < 8; ++j) qf[j] = (float)aq[j];
    float kcls[8], vcls[2][4];
#pragma unroll
    for (int j = 0; j < 8; ++j) kcls[j] = (float)khcls[bh * 32 + g * 8 + j];
    {
        const half_t* vcb = vplain + ((size_t)bh * NTOK + LWIN) * 32;
#pragma unroll
        for (int h2 = 0; h2 < 2; ++h2)
#pragma unroll
            for (int r = 0; r < 4; ++r) vcls[h2][r] = (float)vcb[h2 * 16 + g * 4 + r];
    }

    float mx = -1e30f, l = 0.f;
    f32x4 acc[2] = {{0.f,0.f,0.f,0.f},{0.f,0.f,0.f,0.f}};

    const int* mrow = mask + (b * WINNUM + wi) * WINNUM;
    int mv = (lane < WINNUM) ? mrow[lane] : 0;
    unsigned long long act = __ballot(mv != 0);

    const half_t* kwin = kh + (size_t)bh * (WINNUM * 2560);
    const half_t* vwin = vh + (size_t)bh * (WINNUM * 2304);

    auto stageKV = [&](int bu, int wj) {
        const int4* kg4 = (const int4*)(kwin + wj * 2560);
        const int4* vg4 = (const int4*)(vwin + wj * 2304);
        int4* kl = (int4*)Klds[bu];
        int4* vl = (int4*)Vt[bu];
        kl[tid] = kg4[tid];                                   // K chunks 0..255
        if (tid < 64) kl[tid + 256] = kg4[tid + 256];         // K 256..319
        else          vl[tid - 64] = vg4[tid - 64];           // V 0..191
        int c2 = tid + 192;
        if (c2 < 288) vl[c2] = vg4[c2];                       // V 192..287
    };

    unsigned long long rem = act;
    int buf = 0;
    if (rem) stageKV(0, __builtin_ctzll(rem));
    while (rem) {
        rem &= rem - 1;
        __syncthreads();
        if (rem) stageKV(buf ^ 1, __builtin_ctzll(rem));

        // S^T tiles: st[t4] covers keys 16*t4.. for query column qi
        f32x4 st[4];
#pragma unroll
        for (int t4 = 0; t4 < 4; ++t4) {
            half8 ak = *(const half8*)&Klds[buf][(t4 * 16 + qi) * 40 + g * 8];
            st[t4] = __builtin_amdgcn_mfma_f32_16x16x32_f16(ak, aq, (f32x4){0.f,0.f,0.f,0.f}, 0, 0, 0);
        }
        float tmax = st[0][0];
#pragma unroll
        for (int t4 = 0; t4 < 4; ++t4)
#pragma unroll
            for (int r = 0; r < 4; ++r) tmax = fmaxf(tmax, st[t4][r]);
        tmax = fmaxf(tmax, __shfl_xor(tmax, 16));
        tmax = fmaxf(tmax, __shfl_xor(tmax, 32));
        float mnew = fmaxf(mx, tmax);
        float corr = exp2f(mx - mnew);
        mx = mnew;
        float p[4][4], ls = 0.f;
#pragma unroll
        for (int t4 = 0; t4 < 4; ++t4)
#pragma unroll
            for (int r = 0; r < 4; ++r) { p[t4][r] = exp2f(st[t4][r] - mx); ls += p[t4][r]; }
        ls += __shfl_xor(ls, 16);
        ls += __shfl_xor(ls, 32);
        l = l * corr + ls;
#pragma unroll
        for (int h2 = 0; h2 < 2; ++h2)
#pragma unroll
            for (int r = 0; r < 4; ++r) acc[h2][r] *= corr;
        // P -> LDS fp16 (packed pairs along key)
        {
            short* pw = &Plds[wv][qi * 72];
#pragma unroll
            for (int t4 = 0; t4 < 4; ++t4)
#pragma unroll
                for (int r2 = 0; r2 < 2; ++r2) {
                    unsigned pk = (unsigned)h16(p[t4][2 * r2])
                                | ((unsigned)h16(p[t4][2 * r2 + 1]) << 16);
                    *(unsigned*)&pw[t4 * 16 + g * 4 + r2 * 2] = pk;
                }
        }
        // O^T += V^T . P^T
#pragma unroll
        for (int s2 = 0; s2 < 2; ++s2) {
            half8 bp = *(const half8*)&Plds[wv][qi * 72 + s2 * 32 + g * 8];
#pragma unroll
            for (int h2 = 0; h2 < 2; ++h2) {
                half8 av = *(const half8*)&Vt[buf][(h2 * 16 + qi) * 72 + s2 * 32 + g * 8];
                acc[h2] = __builtin_amdgcn_mfma_f32_16x16x32_f16(av, bp, acc[h2], 0, 0, 0);
            }
        }
        buf ^= 1;
    }

    // cls key (scalar fp32 path, exp2 domain)
    {
        float s = 0.f;
#pragma unroll
        for (int j = 0; j < 8; ++j) s += qf[j] * kcls[j];
        s += __shfl_xor(s, 16);
        s += __shfl_xor(s, 32);
        float mnew = fmaxf(mx, s);
        float corr = exp2f(mx - mnew);
        mx = mnew;
        float pc = exp2f(s - mnew);
        l = l * corr + pc;
#pragma unroll
        for (int h2 = 0; h2 < 2; ++h2)
#pragma unroll
            for (int r = 0; r < 4; ++r) acc[h2][r] = acc[h2][r] * corr + pc * vcls[h2][r];
    }

    // write O to t[pix][nh*32 + d], d = 16*h2 + 4*g + r
    {
        float inv = 1.f / l;
        int kk = wv * 16 + qi;
        int hh = (wi / 7) * 8 + (kk >> 3);
        int ww = (wi % 7) * 8 + (kk & 7);
        size_t pix = (size_t)b * LWIN + hh * 56 + ww;
        half_t* tp = tg + pix * 256 + nh * 32;
#pragma unroll
        for (int h2 = 0; h2 < 2; ++h2) {
            half4 hv;
#pragma unroll
            for (int r = 0; r < 4; ++r) hv[r] = (half_t)(acc[h2][r] * inv);
            *(half4*)(tp + h2 * 16 + g * 4) = hv;
        }
    }
}

// ---------------------------------------------------------------------------
// cls_attn: cls query vs all 3137 keys. One wave per (b, head).
// ---------------------------------------------------------------------------
__global__ __launch_bounds__(64)
void cls_attn(const half_t* __restrict__ qh, const half_t* __restrict__ kh,
              const half_t* __restrict__ khcls, const half_t* __restrict__ vplain,
              half_t* __restrict__ tg)
{
    const int bh = blockIdx.x;
    const int lane = threadIdx.x;
    const int b = bh >> 3, nh = bh & 7;

    float q[32];
    {
        const half_t* qp = qh + ((size_t)bh * NTOK + LWIN) * 32;
#pragma unroll
        for (int d = 0; d < 32; ++d) q[d] = (float)qp[d];
    }
    float mx = -1e30f, l = 0.f, o[32];
#pragma unroll
    for (int d = 0; d < 32; ++d) o[d] = 0.f;

    const half_t* kwin = kh + (size_t)bh * (WINNUM * 2560);
    const half_t* vbase = vplain + (size_t)bh * NTOK * 32;

    for (int it = 0; it < WINNUM; ++it) {
        int k = it * 64 + lane;
        const half_t* kp = kwin + it * 2560 + lane * 40;
        float s = 0.f;
#pragma unroll
        for (int c8 = 0; c8 < 4; ++c8) {
            half8 kv = *(const half8*)(kp + c8 * 8);
#pragma unroll
            for (int j = 0; j < 8; ++j) s += q[c8 * 8 + j] * (float)kv[j];
        }
        float mnew = fmaxf(mx, s);
        float corr = exp2f(mx - mnew);
        float pp = exp2f(s - mnew);
        mx = mnew;
        l = l * corr + pp;
        const half_t* vp = vbase + (size_t)k * 32;
#pragma unroll
        for (int c8 = 0; c8 < 4; ++c8) {
            half8 vv = *(const half8*)(vp + c8 * 8);
#pragma unroll
            for (int j = 0; j < 8; ++j)
                o[c8 * 8 + j] = o[c8 * 8 + j] * corr + pp * (float)vv[j];
        }
    }
    if (lane == 0) {   // cls key
        const half_t* kp = khcls + bh * 32;
        float s = 0.f;
#pragma unroll
        for (int d = 0; d < 32; ++d) s += q[d] * (float)kp[d];
        float mnew = fmaxf(mx, s);
        float corr = exp2f(mx - mnew);
        float pp = exp2f(s - mnew);
        mx = mnew;
        l = l * corr + pp;
        const half_t* vp = vbase + (size_t)LWIN * 32;
#pragma unroll
        for (int d = 0; d < 32; ++d) o[d] = o[d] * corr + pp * (float)vp[d];
    }
#pragma unroll
    for (int off = 1; off < 64; off <<= 1) {
        float m2 = __shfl_xor(mx, off);
        float l2 = __shfl_xor(l, off);
        float mnew = fmaxf(mx, m2);
        float ca = exp2f(mx - mnew), cb = exp2f(m2 - mnew);
        l = l * ca + l2 * cb;
#pragma unroll
        for (int d = 0; d < 32; ++d) {
            float od2 = __shfl_xor(o[d], off);
            o[d] = o[d] * ca + od2 * cb;
        }
        mx = mnew;
    }
    if (lane == 0) {
        float inv = 1.f / l;
        half_t* tp = tg + (size_t)(NPIX + b) * 256 + nh * 32;
#pragma unroll
        for (int d = 0; d < 32; ++d) tp[d] = (half_t)(o[d] * inv);
    }
}

// ---------------------------------------------------------------------------
// lepe_add: t[pix][c..c+7] += depthwise3x3(v) + lepe_b. Thread = (pix, 8 ch).
// ---------------------------------------------------------------------------
__global__ __launch_bounds__(256)
void lepe_add(const half_t* __restrict__ vplain, const float* __restrict__ lk,
              const float* __restrict__ lb, half_t* __restrict__ tg)
{
    const int gidx = blockIdx.x * 256 + threadIdx.x;   // NPIX*32 total
    const int pix = gidx >> 5, cg = gidx & 31;
    const int c0 = cg * 8;
    const int b = pix / LWIN, p = pix - b * LWIN;
    const int hh = p / 56, ww = p - hh * 56;
    const int nh = c0 >> 5, d0 = c0 & 31;
    const half_t* vb = vplain + (size_t)(b * NH + nh) * NTOK * 32 + d0;

    float s[8];
#pragma unroll
    for (int j = 0; j < 8; ++j) s[j] = lb[c0 + j];
#pragma unroll
    for (int dh = -1; dh <= 1; ++dh) {
        int hn = hh + dh;
        if (hn < 0 || hn >= 56) continue;
#pragma unroll
        for (int dw = -1; dw <= 1; ++dw) {
            int wn = ww + dw;
            if (wn < 0 || wn >= 56) continue;
            int tok = ((hn >> 3) * 7 + (wn >> 3)) * 64 + ((hn & 7) << 3) + (wn & 7);
            half8 vv = *(const half8*)(vb + (size_t)tok * 32);
            const float* kk = lk + ((dh + 1) * 3 + (dw + 1)) * 256 + c0;
#pragma unroll
            for (int j = 0; j < 8; ++j) s[j] += (float)vv[j] * kk[j];
        }
    }
    half_t* tp = tg + (size_t)pix * 256 + c0;
    half8 cur = *(const half8*)tp;
    half8 outv;
#pragma unroll
    for (int j = 0; j < 8; ++j) outv[j] = (half_t)((float)cur[j] + s[j]);
    *(half8*)tp = outv;
}

// ---------------------------------------------------------------------------
// out_gemm: out = t @ Wo + bo (fp16 MFMA, fp32 out), same tile structure.
// ---------------------------------------------------------------------------
__global__ __launch_bounds__(256)
void out_gemm(const half_t* __restrict__ th, const half_t* __restrict__ Bt,
              const float* __restrict__ bo, float* __restrict__ out)
{
    __shared__ __align__(16) short As[2][128 * 40];
    __shared__ __align__(16) short Bs[2][128 * 40];
    const int m0 = blockIdx.y * 128, n0 = blockIdx.x * 128;
    const int tid = threadIdx.x;
    const int lane = tid & 63, wv = tid >> 6;
    const int wm = wv >> 1, wn = wv & 1;
    const int qi = lane & 15, g = lane >> 4;
    f32x4 acc[4][4] = {};

    auto stage = [&](int bu, int k0) {
#pragma unroll
        for (int i = 0; i < 2; ++i) {
            int ch = tid + 256 * i;
            int row = ch >> 2, kc = (ch & 3) * 8;
            int m = m0 + row;
            int4 va = (m < MROWS) ? *(const int4*)(th + (size_t)m * 256 + k0 + kc)
                                  : make_int4(0, 0, 0, 0);
            *(int4*)&As[bu][row * 40 + kc] = va;
            int4 vb = *(const int4*)(Bt + (size_t)(n0 + row) * 256 + k0 + kc);
            *(int4*)&Bs[bu][row * 40 + kc] = vb;
        }
    };

    stage(0, 0);
    int buf = 0;
    for (int s = 0; s < 8; ++s) {
        __syncthreads();
        if (s < 7) stage(buf ^ 1, (s + 1) * 32);
        half8 af[4], bf[4];
#pragma unroll
        for (int f = 0; f < 4; ++f) {
            af[f] = *(const half8*)&As[buf][(wm * 64 + f * 16 + qi) * 40 + g * 8];
            bf[f] = *(const half8*)&Bs[buf][(wn * 64 + f * 16 + qi) * 40 + g * 8];
        }
#pragma unroll
        for (int fm = 0; fm < 4; ++fm)
#pragma unroll
            for (int fn = 0; fn < 4; ++fn)
                acc[fm][fn] = __builtin_amdgcn_mfma_f32_16x16x32_f16(af[fm], bf[fn], acc[fm][fn], 0, 0, 0);
        buf ^= 1;
    }

    float bov[4];
    int nn[4];
#pragma unroll
    for (int fn = 0; fn < 4; ++fn) {
        nn[fn] = n0 + wn * 64 + fn * 16 + qi;
        bov[fn] = bo[nn[fn]];
    }
#pragma unroll
    for (int fm = 0; fm < 4; ++fm)
#pragma unroll
        for (int r = 0; r < 4; ++r) {
            int m = m0 + wm * 64 + fm * 16 + g * 4 + r;
            if (m >= MROWS) continue;
#pragma unroll
            for (int fn = 0; fn < 4; ++fn)
                out[(size_t)m * 256 + nn[fn]] = acc[fm][fn][r] + bov[fn];
        }
}

// ---------------------------------------------------------------------------
extern "C" void kernel_launch(void* const* d_in, const int* in_sizes, int n_in,
                              void* d_out, int out_size, void* d_ws, size_t ws_size,
                              hipStream_t stream)
{
    const float* x    = (const float*)d_in[0];
    const float* cls  = (const float*)d_in[1];
    const int*   mask = (const int*)d_in[2];
    const float* Wqkv = (const float*)d_in[5];
    const float* bqkv = (const float*)d_in[6];
    const float* Wo   = (const float*)d_in[7];
    const float* bo   = (const float*)d_in[8];
    const float* lk   = (const float*)d_in[9];
    const float* lb   = (const float*)d_in[10];
    float* out = (float*)d_out;

    char* w = (char*)d_ws;
    half_t* xh     = (half_t*)w;  w += 6424576;   // 12548*256*2
    half_t* qh     = (half_t*)w;  w += 6424576;   // 32*3137*32*2
    half_t* kh     = (half_t*)w;  w += 8028160;   // 32*49*2560*2
    half_t* khcls  = (half_t*)w;  w += 2048;      // 32*32*2
    half_t* vh     = (half_t*)w;  w += 7225344;   // 32*49*2304*2
    half_t* vplain = (half_t*)w;  w += 6424576;
    half_t* Wqkvt  = (half_t*)w;  w += 393216;    // 768*256*2
    half_t* Wot    = (half_t*)w;  w += 131072;    // 256*256*2
    half_t* th     = (half_t*)w;  w += 6424576;   // 12548*256*2

    prep<<<2048, 256, 0, stream>>>(x, cls, Wqkv, Wo, xh, Wqkvt, Wot);
    qkv_gemm<<<dim3(6, 99), 256, 0, stream>>>(xh, Wqkvt, bqkv, qh, kh, khcls, vh, vplain);
    win_attn<<<dim3(WINNUM, NH, B_), 256, 0, stream>>>(qh, kh, khcls, vh, vplain, mask, th);
    cls_attn<<<32, 64, 0, stream>>>(qh, kh, khcls, vplain, th);
    lepe_add<<<1568, 256, 0, stream>>>(vplain, lk, lb, th);
    out_gemm<<<dim3(2, 99), 256, 0, stream>>>(th, Wot, bo, out);
}

// Round 5
// 181.075 us; speedup vs baseline: 5.7135x; 1.0894x over previous
//
#include <hip/hip_runtime.h>
#include <math.h>

#define B_      4
#define NH      8
#define HD      32
#define WINNUM  49
#define LWIN    3136
#define NTOK    3137
#define NPIX    12544     // B * 56 * 56
#define MROWS   12548     // NPIX + 4 cls rows
// 256^-0.5 * log2(e): scores land in exp2 domain
#define SCALE_L2E 0.09016844005556021f
#define SM_BIAS   4.0f    // fixed softmax bias (cancels in normalization)

typedef _Float16 half_t;
using half8 = __attribute__((ext_vector_type(8))) half_t;
using half4 = __attribute__((ext_vector_type(4))) half_t;
using f32x4 = __attribute__((ext_vector_type(4))) float;

__device__ __forceinline__ unsigned pack2(float a, float b) {
    auto h = __builtin_amdgcn_cvt_pkrtz(a, b);   // __fp16 ext_vector(2)
    return __builtin_bit_cast(unsigned, h);
}

// ---------------------------------------------------------------------------
// prep: weight conversions only. Wqkvt (768,256), Wot (256,256), transposed
// (row = output col, k contiguous), fp16.
// ---------------------------------------------------------------------------
__global__ __launch_bounds__(256)
void prep(const float* __restrict__ Wqkv, const float* __restrict__ Wo,
          half_t* __restrict__ Wqkvt, half_t* __restrict__ Wot)
{
    const int idx = blockIdx.x * 256 + threadIdx.x;
    const int stride = gridDim.x * 256;
    for (int i = idx; i < 768 * 256; i += stride) {
        int n = i >> 8, k = i & 255;
        Wqkvt[i] = (half_t)Wqkv[k * 768 + n];
    }
    for (int i = idx; i < 256 * 256; i += stride) {
        int n = i >> 8, k = i & 255;
        Wot[i] = (half_t)Wo[k * 256 + n];
    }
}

// ---------------------------------------------------------------------------
// qkv_gemm: C = [x;cls] @ Wqkv + bqkv via fp16 MFMA, 128x128 tile, 4 waves.
// A staged directly from fp32 with cvt_pkrtz. Epilogue scatters:
//   q -> qh (scaled, exp2 domain), k -> kh [49][64][40] + khcls,
//   v -> vplain + vh [49][32][80] (transposed, padded).
// ---------------------------------------------------------------------------
__global__ __launch_bounds__(256)
void qkv_gemm(const float* __restrict__ x, const float* __restrict__ cls,
              const half_t* __restrict__ Bt, const float* __restrict__ bqkv,
              half_t* __restrict__ qh, half_t* __restrict__ kh,
              half_t* __restrict__ khcls, half_t* __restrict__ vh,
              half_t* __restrict__ vplain)
{
    __shared__ __align__(16) short As[2][128 * 40];
    __shared__ __align__(16) short Bs[2][128 * 40];
    const int m0 = blockIdx.y * 128, n0 = blockIdx.x * 128;
    const int tid = threadIdx.x;
    const int lane = tid & 63, wv = tid >> 6;
    const int wm = wv >> 1, wn = wv & 1;
    const int qi = lane & 15, g = lane >> 4;
    f32x4 acc[4][4] = {};

    auto stage = [&](int bu, int k0) {
#pragma unroll
        for (int i = 0; i < 2; ++i) {
            int ch = tid + 256 * i;
            int row = ch >> 2, kc = (ch & 3) * 8;
            int m = m0 + row;
            uint4 pa = make_uint4(0u, 0u, 0u, 0u);
            if (m < MROWS) {
                const float* src = ((m < NPIX) ? (x + (size_t)m * 256)
                                               : (cls + (size_t)(m - NPIX) * 256)) + k0 + kc;
                float4 f0 = *(const float4*)src;
                float4 f1 = *(const float4*)(src + 4);
                pa = make_uint4(pack2(f0.x, f0.y), pack2(f0.z, f0.w),
                                pack2(f1.x, f1.y), pack2(f1.z, f1.w));
            }
            *(uint4*)&As[bu][row * 40 + kc] = pa;
            int4 vb = *(const int4*)(Bt + (size_t)(n0 + row) * 256 + k0 + kc);
            *(int4*)&Bs[bu][row * 40 + kc] = vb;
        }
    };

    stage(0, 0);
    int buf = 0;
    for (int s = 0; s < 8; ++s) {
        __syncthreads();
        if (s < 7) stage(buf ^ 1, (s + 1) * 32);
        half8 af[4], bf[4];
#pragma unroll
        for (int f = 0; f < 4; ++f) {
            af[f] = *(const half8*)&As[buf][(wm * 64 + f * 16 + qi) * 40 + g * 8];
            bf[f] = *(const half8*)&Bs[buf][(wn * 64 + f * 16 + qi) * 40 + g * 8];
        }
#pragma unroll
        for (int fm = 0; fm < 4; ++fm)
#pragma unroll
            for (int fn = 0; fn < 4; ++fn)
                acc[fm][fn] = __builtin_amdgcn_mfma_f32_16x16x32_f16(af[fm], bf[fn], acc[fm][fn], 0, 0, 0);
        buf ^= 1;
    }

    const int part = n0 >> 8;   // tiles don't straddle 256-col boundaries
    int nhv[4], dv[4];
    float bq[4];
#pragma unroll
    for (int fn = 0; fn < 4; ++fn) {
        int n = n0 + wn * 64 + fn * 16 + qi;
        bq[fn] = bqkv[n];
        int c = n & 255;
        nhv[fn] = c >> 5; dv[fn] = c & 31;
    }
#pragma unroll
    for (int fm = 0; fm < 4; ++fm) {
#pragma unroll
        for (int r = 0; r < 4; ++r) {
            int m = m0 + wm * 64 + fm * 16 + g * 4 + r;
            if (m >= MROWS) continue;
            int b, tok;
            if (m < NPIX) {
                b = m / LWIN;
                int p = m - b * LWIN;
                int hh = p / 56, ww = p - hh * 56;
                tok = ((hh >> 3) * 7 + (ww >> 3)) * 64 + ((hh & 7) << 3) + (ww & 7);
            } else { b = m - NPIX; tok = LWIN; }
#pragma unroll
            for (int fn = 0; fn < 4; ++fn) {
                float val = acc[fm][fn][r] + bq[fn];
                size_t bh = (size_t)(b * NH + nhv[fn]);
                int d = dv[fn];
                if (part == 0) {
                    qh[(bh * NTOK + tok) * 32 + d] = (half_t)(val * SCALE_L2E);
                } else if (part == 1) {
                    if (tok < LWIN) kh[(bh * WINNUM + (tok >> 6)) * 2560 + (tok & 63) * 40 + d] = (half_t)val;
                    else            khcls[bh * 32 + d] = (half_t)val;
                } else {
                    vplain[(bh * NTOK + tok) * 32 + d] = (half_t)val;
                    if (tok < LWIN) vh[(bh * WINNUM + (tok >> 6)) * 2560 + d * 80 + (tok & 63)] = (half_t)val;
                }
            }
        }
    }
}

// ---------------------------------------------------------------------------
// win_attn: fp16 MFMA block-sparse window attention.
// Reg-staged K/V (issue loads before compute, ds_write after -> latency
// hidden), one barrier per window, fixed-bias softmax (no online max).
// XCD-chunked block swizzle. Writes O directly to t[pix][256] (fp16).
// ---------------------------------------------------------------------------
__global__ __launch_bounds__(256)
void win_attn(const half_t* __restrict__ qh, const half_t* __restrict__ kh,
              const half_t* __restrict__ khcls, const half_t* __restrict__ vh,
              const half_t* __restrict__ vplain, const int* __restrict__ mask,
              half_t* __restrict__ tg)
{
    // swizzle: 1568 = 8 * 196; XCD k gets contiguous chunk of 196 blocks
    const int id = blockIdx.x;
    const int sw = (id & 7) * 196 + (id >> 3);
    const int wi = sw % 49;
    const int bh = sw / 49;
    const int b = bh >> 3, nh = bh & 7;
    const int tid = threadIdx.x;

    __shared__ __align__(16) int4 KV[2][640];       // K: [64][40] sh, V: [32][80] sh
    __shared__ __align__(16) short Plds[4][16 * 72];

    const int lane = tid & 63, wv = tid >> 6;
    const int g = lane >> 4, qi = lane & 15;
    const int qrow = wi * 64 + wv * 16 + qi;

    half8 aq = *(const half8*)(qh + ((size_t)bh * NTOK + qrow) * 32 + g * 8);
    float qf[8];
#pragma unroll
    for (int j = 0; j < 8; ++j) qf[j] = (float)aq[j];
    float kcls[8], vcls[2][4];
#pragma unroll
    for (int j = 0; j < 8; ++j) kcls[j] = (float)khcls[bh * 32 + g * 8 + j];
    {
        const half_t* vcb = vplain + ((size_t)bh * NTOK + LWIN) * 32;
#pragma unroll
        for (int h2 = 0; h2 < 2; ++h2)
#pragma unroll
            for (int r = 0; r < 4; ++r) vcls[h2][r] = (float)vcb[h2 * 16 + g * 4 + r];
    }

    float lacc = 0.f;
    f32x4 acc[2] = {{0.f,0.f,0.f,0.f},{0.f,0.f,0.f,0.f}};

    const int* mrow = mask + (b * WINNUM + wi) * WINNUM;
    int mv = (lane < WINNUM) ? mrow[lane] : 0;
    unsigned long long rem = __ballot(mv != 0);

    const int4* kwin = (const int4*)(kh + (size_t)bh * (WINNUM * 2560));
    const int4* vwin = (const int4*)(vh + (size_t)bh * (WINNUM * 2560));

    int4 r0, r1, r2;
    auto issue = [&](int wj) {
        const int4* kg4 = kwin + wj * 320;
        const int4* vg4 = vwin + wj * 320;
        r0 = kg4[tid];
        r1 = (tid < 64) ? kg4[tid + 256] : vg4[tid - 64];
        if (tid < 128) r2 = vg4[tid + 192];
    };
    auto commit = [&](int bu) {
        KV[bu][tid] = r0;
        KV[bu][tid + 256] = r1;
        if (tid < 128) KV[bu][tid + 512] = r2;
    };

    int buf = 0;
    if (rem) { issue(__builtin_ctzll(rem)); commit(0); }
    __syncthreads();

    while (rem) {
        rem &= rem - 1;
        if (rem) issue(__builtin_ctzll(rem));   // loads for NEXT window in flight

        const short* Kb = (const short*)&KV[buf][0];
        const short* Vb = (const short*)&KV[buf][320];

        // S^T tiles: st[t4] covers keys 16*t4.. for query column qi
        f32x4 st[4];
#pragma unroll
        for (int t4 = 0; t4 < 4; ++t4) {
            half8 ak = *(const half8*)&Kb[(t4 * 16 + qi) * 40 + g * 8];
            st[t4] = __builtin_amdgcn_mfma_f32_16x16x32_f16(ak, aq, (f32x4){0.f,0.f,0.f,0.f}, 0, 0, 0);
        }
        // fixed-bias softmax: p = exp2(s - SM_BIAS); l reduce deferred
        float p[4][4];
#pragma unroll
        for (int t4 = 0; t4 < 4; ++t4)
#pragma unroll
            for (int r = 0; r < 4; ++r) {
                p[t4][r] = exp2f(st[t4][r] - SM_BIAS);
                lacc += p[t4][r];
            }
        // P -> LDS fp16 (cvt_pkrtz pairs along key)
        {
            short* pw = &Plds[wv][qi * 72];
#pragma unroll
            for (int t4 = 0; t4 < 4; ++t4)
#pragma unroll
                for (int r2 = 0; r2 < 2; ++r2)
                    *(unsigned*)&pw[t4 * 16 + g * 4 + r2 * 2] = pack2(p[t4][2 * r2], p[t4][2 * r2 + 1]);
        }
        // O^T += V^T . P^T
#pragma unroll
        for (int s2 = 0; s2 < 2; ++s2) {
            half8 bp = *(const half8*)&Plds[wv][qi * 72 + s2 * 32 + g * 8];
#pragma unroll
            for (int h2 = 0; h2 < 2; ++h2) {
                half8 av = *(const half8*)&Vb[(h2 * 16 + qi) * 80 + s2 * 32 + g * 8];
                acc[h2] = __builtin_amdgcn_mfma_f32_16x16x32_f16(av, bp, acc[h2], 0, 0, 0);
            }
        }

        if (rem) commit(buf ^ 1);
        __syncthreads();
        buf ^= 1;
    }

    // cls key (fp32 scalar, same bias)
    float pc;
    {
        float sc = 0.f;
#pragma unroll
        for (int j = 0; j < 8; ++j) sc += qf[j] * kcls[j];
        sc += __shfl_xor(sc, 16);
        sc += __shfl_xor(sc, 32);
        pc = exp2f(sc - SM_BIAS);
    }
    // final l reduction across the 4 g-lanes, + cls
    lacc += __shfl_xor(lacc, 16);
    lacc += __shfl_xor(lacc, 32);
    float l = lacc + pc;
#pragma unroll
    for (int h2 = 0; h2 < 2; ++h2)
#pragma unroll
        for (int r = 0; r < 4; ++r) acc[h2][r] += pc * vcls[h2][r];

    // write O to t[pix][nh*32 + d], d = 16*h2 + 4*g + r
    {
        float inv = 1.f / l;
        int kk = wv * 16 + qi;
        int hh = (wi / 7) * 8 + (kk >> 3);
        int ww = (wi % 7) * 8 + (kk & 7);
        size_t pix = (size_t)b * LWIN + hh * 56 + ww;
        half_t* tp = tg + pix * 256 + nh * 32;
#pragma unroll
        for (int h2 = 0; h2 < 2; ++h2) {
            half4 hv;
#pragma unroll
            for (int r = 0; r < 4; ++r) hv[r] = (half_t)(acc[h2][r] * inv);
            *(half4*)(tp + h2 * 16 + g * 4) = hv;
        }
    }
}

// ---------------------------------------------------------------------------
// cls_attn: cls query vs all 3137 keys. One wave per (b, head). Fixed bias.
// ---------------------------------------------------------------------------
__global__ __launch_bounds__(64)
void cls_attn(const half_t* __restrict__ qh, const half_t* __restrict__ kh,
              const half_t* __restrict__ khcls, const half_t* __restrict__ vplain,
              half_t* __restrict__ tg)
{
    const int bh = blockIdx.x;
    const int lane = threadIdx.x;
    const int b = bh >> 3, nh = bh & 7;

    float q[32];
    {
        const half_t* qp = qh + ((size_t)bh * NTOK + LWIN) * 32;
#pragma unroll
        for (int d = 0; d < 32; ++d) q[d] = (float)qp[d];
    }
    float l = 0.f, o[32];
#pragma unroll
    for (int d = 0; d < 32; ++d) o[d] = 0.f;

    const half_t* kwin = kh + (size_t)bh * (WINNUM * 2560);
    const half_t* vbase = vplain + (size_t)bh * NTOK * 32;

    for (int it = 0; it < WINNUM; ++it) {
        int k = it * 64 + lane;
        const half_t* kp = kwin + it * 2560 + lane * 40;
        float s = 0.f;
#pragma unroll
        for (int c8 = 0; c8 < 4; ++c8) {
            half8 kv = *(const half8*)(kp + c8 * 8);
#pragma unroll
            for (int j = 0; j < 8; ++j) s += q[c8 * 8 + j] * (float)kv[j];
        }
        float pp = exp2f(s - SM_BIAS);
        l += pp;
        const half_t* vp = vbase + (size_t)k * 32;
#pragma unroll
        for (int c8 = 0; c8 < 4; ++c8) {
            half8 vv = *(const half8*)(vp + c8 * 8);
#pragma unroll
            for (int j = 0; j < 8; ++j)
                o[c8 * 8 + j] += pp * (float)vv[j];
        }
    }
    if (lane == 0) {   // cls key
        const half_t* kp = khcls + bh * 32;
        float s = 0.f;
#pragma unroll
        for (int d = 0; d < 32; ++d) s += q[d] * (float)kp[d];
        float pp = exp2f(s - SM_BIAS);
        l += pp;
        const half_t* vp = vbase + (size_t)LWIN * 32;
#pragma unroll
        for (int d = 0; d < 32; ++d) o[d] += pp * (float)vp[d];
    }
#pragma unroll
    for (int off = 1; off < 64; off <<= 1) {
        l += __shfl_xor(l, off);
#pragma unroll
        for (int d = 0; d < 32; ++d) o[d] += __shfl_xor(o[d], off);
    }
    if (lane == 0) {
        float inv = 1.f / l;
        half_t* tp = tg + (size_t)(NPIX + b) * 256 + nh * 32;
#pragma unroll
        for (int d = 0; d < 32; ++d) tp[d] = (half_t)(o[d] * inv);
    }
}

// ---------------------------------------------------------------------------
// lepe_add: t[pix][c..c+7] += depthwise3x3(v) + lepe_b. Thread = (pix, 8 ch).
// ---------------------------------------------------------------------------
__global__ __launch_bounds__(256)
void lepe_add(const half_t* __restrict__ vplain, const float* __restrict__ lk,
              const float* __restrict__ lb, half_t* __restrict__ tg)
{
    const int gidx = blockIdx.x * 256 + threadIdx.x;   // NPIX*32 total
    const int pix = gidx >> 5, cg = gidx & 31;
    const int c0 = cg * 8;
    const int b = pix / LWIN, p = pix - b * LWIN;
    const int hh = p / 56, ww = p - hh * 56;
    const int nh = c0 >> 5, d0 = c0 & 31;
    const half_t* vb = vplain + (size_t)(b * NH + nh) * NTOK * 32 + d0;

    float s[8];
#pragma unroll
    for (int j = 0; j < 8; ++j) s[j] = lb[c0 + j];
#pragma unroll
    for (int dh = -1; dh <= 1; ++dh) {
        int hn = hh + dh;
        if (hn < 0 || hn >= 56) continue;
#pragma unroll
        for (int dw = -1; dw <= 1; ++dw) {
            int wn = ww + dw;
            if (wn < 0 || wn >= 56) continue;
            int tok = ((hn >> 3) * 7 + (wn >> 3)) * 64 + ((hn & 7) << 3) + (wn & 7);
            half8 vv = *(const half8*)(vb + (size_t)tok * 32);
            const float* kk = lk + ((dh + 1) * 3 + (dw + 1)) * 256 + c0;
#pragma unroll
            for (int j = 0; j < 8; ++j) s[j] += (float)vv[j] * kk[j];
        }
    }
    half_t* tp = tg + (size_t)pix * 256 + c0;
    half8 cur = *(const half8*)tp;
    half8 outv;
#pragma unroll
    for (int j = 0; j < 8; ++j) outv[j] = (half_t)((float)cur[j] + s[j]);
    *(half8*)tp = outv;
}

// ---------------------------------------------------------------------------
// out_gemm: out = t @ Wo + bo (fp16 MFMA, fp32 out).
// ---------------------------------------------------------------------------
__global__ __launch_bounds__(256)
void out_gemm(const half_t* __restrict__ th, const half_t* __restrict__ Bt,
              const float* __restrict__ bo, float* __restrict__ out)
{
    __shared__ __align__(16) short As[2][128 * 40];
    __shared__ __align__(16) short Bs[2][128 * 40];
    const int m0 = blockIdx.y * 128, n0 = blockIdx.x * 128;
    const int tid = threadIdx.x;
    const int lane = tid & 63, wv = tid >> 6;
    const int wm = wv >> 1, wn = wv & 1;
    const int qi = lane & 15, g = lane >> 4;
    f32x4 acc[4][4] = {};

    auto stage = [&](int bu, int k0) {
#pragma unroll
        for (int i = 0; i < 2; ++i) {
            int ch = tid + 256 * i;
            int row = ch >> 2, kc = (ch & 3) * 8;
            int m = m0 + row;
            int4 va = (m < MROWS) ? *(const int4*)(th + (size_t)m * 256 + k0 + kc)
                                  : make_int4(0, 0, 0, 0);
            *(int4*)&As[bu][row * 40 + kc] = va;
            int4 vb = *(const int4*)(Bt + (size_t)(n0 + row) * 256 + k0 + kc);
            *(int4*)&Bs[bu][row * 40 + kc] = vb;
        }
    };

    stage(0, 0);
    int buf = 0;
    for (int s = 0; s < 8; ++s) {
        __syncthreads();
        if (s < 7) stage(buf ^ 1, (s + 1) * 32);
        half8 af[4], bf[4];
#pragma unroll
        for (int f = 0; f < 4; ++f) {
            af[f] = *(const half8*)&As[buf][(wm * 64 + f * 16 + qi) * 40 + g * 8];
            bf[f] = *(const half8*)&Bs[buf][(wn * 64 + f * 16 + qi) * 40 + g * 8];
        }
#pragma unroll
        for (int fm = 0; fm < 4; ++fm)
#pragma unroll
            for (int fn = 0; fn < 4; ++fn)
                acc[fm][fn] = __builtin_amdgcn_mfma_f32_16x16x32_f16(af[fm], bf[fn], acc[fm][fn], 0, 0, 0);
        buf ^= 1;
    }

    float bov[4];
    int nn[4];
#pragma unroll
    for (int fn = 0; fn < 4; ++fn) {
        nn[fn] = n0 + wn * 64 + fn * 16 + qi;
        bov[fn] = bo[nn[fn]];
    }
#pragma unroll
    for (int fm = 0; fm < 4; ++fm)
#pragma unroll
        for (int r = 0; r < 4; ++r) {
            int m = m0 + wm * 64 + fm * 16 + g * 4 + r;
            if (m >= MROWS) continue;
#pragma unroll
            for (int fn = 0; fn < 4; ++fn)
                out[(size_t)m * 256 + nn[fn]] = acc[fm][fn][r] + bov[fn];
        }
}

// ---------------------------------------------------------------------------
extern "C" void kernel_launch(void* const* d_in, const int* in_sizes, int n_in,
                              void* d_out, int out_size, void* d_ws, size_t ws_size,
                              hipStream_t stream)
{
    const float* x    = (const float*)d_in[0];
    const float* cls  = (const float*)d_in[1];
    const int*   mask = (const int*)d_in[2];
    const float* Wqkv = (const float*)d_in[5];
    const float* bqkv = (const float*)d_in[6];
    const float* Wo   = (const float*)d_in[7];
    const float* bo   = (const float*)d_in[8];
    const float* lk   = (const float*)d_in[9];
    const float* lb   = (const float*)d_in[10];
    float* out = (float*)d_out;

    char* w = (char*)d_ws;
    half_t* qh     = (half_t*)w;  w += 6424576;   // 32*3137*32*2
    half_t* kh     = (half_t*)w;  w += 8028160;   // 32*49*2560*2
    half_t* khcls  = (half_t*)w;  w += 2048;      // 32*32*2
    half_t* vh     = (half_t*)w;  w += 8028160;   // 32*49*2560*2
    half_t* vplain = (half_t*)w;  w += 6424576;
    half_t* Wqkvt  = (half_t*)w;  w += 393216;    // 768*256*2
    half_t* Wot    = (half_t*)w;  w += 131072;    // 256*256*2
    half_t* th     = (half_t*)w;  w += 6424576;   // 12548*256*2

    prep<<<512, 256, 0, stream>>>(Wqkv, Wo, Wqkvt, Wot);
    qkv_gemm<<<dim3(6, 99), 256, 0, stream>>>(x, cls, Wqkvt, bqkv, qh, kh, khcls, vh, vplain);
    win_attn<<<1568, 256, 0, stream>>>(qh, kh, khcls, vh, vplain, mask, th);
    cls_attn<<<32, 64, 0, stream>>>(qh, kh, khcls, vplain, th);
    lepe_add<<<1568, 256, 0, stream>>>(vplain, lk, lb, th);
    out_gemm<<<dim3(2, 99), 256, 0, stream>>>(th, Wot, bo, out);
}

// Round 6
// 125.305 us; speedup vs baseline: 8.2565x; 1.4451x over previous
//
#include <hip/hip_runtime.h>
#include <math.h>

#define B_      4
#define NH      8
#define HD      32
#define WINNUM  49
#define LWIN    3136
#define NTOK    3137
#define NPIX    12544     // B * 56 * 56
#define MROWS   12548     // NPIX + 4 cls rows
// 256^-0.5 * log2(e): scores land in exp2 domain
#define SCALE_L2E 0.09016844005556021f
#define SM_BIAS   4.0f    // fixed softmax bias (cancels in normalization)

typedef _Float16 half_t;
using half8 = __attribute__((ext_vector_type(8))) half_t;
using half4 = __attribute__((ext_vector_type(4))) half_t;
using f32x4 = __attribute__((ext_vector_type(4))) float;

__device__ __forceinline__ unsigned pack2(float a, float b) {
    auto h = __builtin_amdgcn_cvt_pkrtz(a, b);   // __fp16 ext_vector(2)
    return __builtin_bit_cast(unsigned, h);
}

// ---------------------------------------------------------------------------
// prep: xh = fp16([x;cls]) (12548,256); Wqkvt (768,256) and Wot (256,256)
// transposed fp16 (row = output col, k contiguous).
// ---------------------------------------------------------------------------
__global__ __launch_bounds__(256)
void prep(const float* __restrict__ x, const float* __restrict__ cls,
          const float* __restrict__ Wqkv, const float* __restrict__ Wo,
          half_t* __restrict__ xh, half_t* __restrict__ Wqkvt, half_t* __restrict__ Wot)
{
    const int idx = blockIdx.x * 256 + threadIdx.x;
    const int stride = gridDim.x * 256;
    for (int i = idx; i < MROWS * 256; i += stride) {
        int row = i >> 8, c = i & 255;
        float v = (row < NPIX) ? x[i] : cls[(row - NPIX) * 256 + c];
        xh[i] = (half_t)v;
    }
    for (int i = idx; i < 768 * 256; i += stride) {
        int n = i >> 8, k = i & 255;
        Wqkvt[i] = (half_t)Wqkv[k * 768 + n];
    }
    for (int i = idx; i < 256 * 256; i += stride) {
        int n = i >> 8, k = i & 255;
        Wot[i] = (half_t)Wo[k * 256 + n];
    }
}

// ---------------------------------------------------------------------------
// qkv_gemm: C = xh @ Wqkv + bqkv via fp16 MFMA, 128x128 tile, 4 waves.
// Reg-staged double buffer: loads for phase s+1 issued before phase s MFMAs.
// Epilogue scatters q -> qh (scaled), k -> kh [49][64][40] + khcls,
// v -> vplain + vh [49][32][80] (transposed, padded).
// ---------------------------------------------------------------------------
__global__ __launch_bounds__(256)
void qkv_gemm(const half_t* __restrict__ xh, const half_t* __restrict__ Bt,
              const float* __restrict__ bqkv,
              half_t* __restrict__ qh, half_t* __restrict__ kh,
              half_t* __restrict__ khcls, half_t* __restrict__ vh,
              half_t* __restrict__ vplain)
{
    __shared__ __align__(16) short As[2][128 * 40];
    __shared__ __align__(16) short Bs[2][128 * 40];
    const int m0 = blockIdx.y * 128, n0 = blockIdx.x * 128;
    const int tid = threadIdx.x;
    const int lane = tid & 63, wv = tid >> 6;
    const int wm = wv >> 1, wn = wv & 1;
    const int qi = lane & 15, g = lane >> 4;
    f32x4 acc[4][4] = {};

    int4 ra[2], rb[2];
    auto issue = [&](int k0) {
#pragma unroll
        for (int i = 0; i < 2; ++i) {
            int ch = tid + 256 * i;
            int row = ch >> 2, kc = (ch & 3) * 8;
            int m = m0 + row;
            ra[i] = (m < MROWS) ? *(const int4*)(xh + (size_t)m * 256 + k0 + kc)
                                : make_int4(0, 0, 0, 0);
            rb[i] = *(const int4*)(Bt + (size_t)(n0 + row) * 256 + k0 + kc);
        }
    };
    auto commit = [&](int bu) {
#pragma unroll
        for (int i = 0; i < 2; ++i) {
            int ch = tid + 256 * i;
            int row = ch >> 2, kc = (ch & 3) * 8;
            *(int4*)&As[bu][row * 40 + kc] = ra[i];
            *(int4*)&Bs[bu][row * 40 + kc] = rb[i];
        }
    };

    issue(0); commit(0);
    __syncthreads();
    int buf = 0;
    for (int s = 0; s < 8; ++s) {
        if (s < 7) issue((s + 1) * 32);
        half8 af[4], bf[4];
#pragma unroll
        for (int f = 0; f < 4; ++f) {
            af[f] = *(const half8*)&As[buf][(wm * 64 + f * 16 + qi) * 40 + g * 8];
            bf[f] = *(const half8*)&Bs[buf][(wn * 64 + f * 16 + qi) * 40 + g * 8];
        }
#pragma unroll
        for (int fm = 0; fm < 4; ++fm)
#pragma unroll
            for (int fn = 0; fn < 4; ++fn)
                acc[fm][fn] = __builtin_amdgcn_mfma_f32_16x16x32_f16(af[fm], bf[fn], acc[fm][fn], 0, 0, 0);
        if (s < 7) commit(buf ^ 1);
        __syncthreads();
        buf ^= 1;
    }

    const int part = n0 >> 8;   // tiles don't straddle 256-col boundaries
    int nhv[4], dv[4];
    float bq[4];
#pragma unroll
    for (int fn = 0; fn < 4; ++fn) {
        int n = n0 + wn * 64 + fn * 16 + qi;
        bq[fn] = bqkv[n];
        int c = n & 255;
        nhv[fn] = c >> 5; dv[fn] = c & 31;
    }
#pragma unroll
    for (int fm = 0; fm < 4; ++fm) {
#pragma unroll
        for (int r = 0; r < 4; ++r) {
            int m = m0 + wm * 64 + fm * 16 + g * 4 + r;
            if (m >= MROWS) continue;
            int b, tok;
            if (m < NPIX) {
                b = m / LWIN;
                int p = m - b * LWIN;
                int hh = p / 56, ww = p - hh * 56;
                tok = ((hh >> 3) * 7 + (ww >> 3)) * 64 + ((hh & 7) << 3) + (ww & 7);
            } else { b = m - NPIX; tok = LWIN; }
#pragma unroll
            for (int fn = 0; fn < 4; ++fn) {
                float val = acc[fm][fn][r] + bq[fn];
                size_t bh = (size_t)(b * NH + nhv[fn]);
                int d = dv[fn];
                if (part == 0) {
                    qh[(bh * NTOK + tok) * 32 + d] = (half_t)(val * SCALE_L2E);
                } else if (part == 1) {
                    if (tok < LWIN) kh[(bh * WINNUM + (tok >> 6)) * 2560 + (tok & 63) * 40 + d] = (half_t)val;
                    else            khcls[bh * 32 + d] = (half_t)val;
                } else {
                    vplain[(bh * NTOK + tok) * 32 + d] = (half_t)val;
                    if (tok < LWIN) vh[(bh * WINNUM + (tok >> 6)) * 2560 + d * 80 + (tok & 63)] = (half_t)val;
                }
            }
        }
    }
}

// ---------------------------------------------------------------------------
// win_attn (+fused cls partials): blocks [0,1568) do window attention;
// blocks [1568,1824) compute cls-query partial sums over key chunks
// (deterministic per-slot writes, no atomics).
// ---------------------------------------------------------------------------
__global__ __launch_bounds__(256)
void win_attn(const half_t* __restrict__ qh, const half_t* __restrict__ kh,
              const half_t* __restrict__ khcls, const half_t* __restrict__ vh,
              const half_t* __restrict__ vplain, const int* __restrict__ mask,
              half_t* __restrict__ tg, float* __restrict__ clspart)
{
    const int id = blockIdx.x;
    const int tid = threadIdx.x;
    __shared__ __align__(16) int4 KV[2][640];       // K: [64][40] sh, V: [32][80] sh
    __shared__ __align__(16) short Plds[4][16 * 72];
    const int lane = tid & 63, wv = tid >> 6;

    if (id >= 1568) {
        // ---------------- cls partial block ----------------
        const int cid = id - 1568;       // 0..255
        const int bh = cid >> 3;         // 0..31
        const int chunk = cid & 7;       // 0..7
        const int wstart = chunk * 6;
        const int nw = (chunk < 7) ? 6 : 7;
        const int nkeys = nw * 64;

        float q[32];
        {
            const half_t* qp = qh + ((size_t)bh * NTOK + LWIN) * 32;
#pragma unroll
            for (int d = 0; d < 32; ++d) q[d] = (float)qp[d];
        }
        float l = 0.f, o[32];
#pragma unroll
        for (int d = 0; d < 32; ++d) o[d] = 0.f;

        const half_t* kwb = kh + (size_t)bh * (WINNUM * 2560) + wstart * 2560;
        const half_t* vb  = vplain + ((size_t)bh * NTOK + wstart * 64) * 32;

        for (int kk = tid; kk < nkeys; kk += 256) {
            const half_t* kp = kwb + (kk >> 6) * 2560 + (kk & 63) * 40;
            float s = 0.f;
#pragma unroll
            for (int c8 = 0; c8 < 4; ++c8) {
                half8 kv = *(const half8*)(kp + c8 * 8);
#pragma unroll
                for (int j = 0; j < 8; ++j) s += q[c8 * 8 + j] * (float)kv[j];
            }
            float pp = exp2f(s - SM_BIAS);
            l += pp;
            const half_t* vp = vb + (size_t)kk * 32;
#pragma unroll
            for (int c8 = 0; c8 < 4; ++c8) {
                half8 vv = *(const half8*)(vp + c8 * 8);
#pragma unroll
                for (int j = 0; j < 8; ++j) o[c8 * 8 + j] += pp * (float)vv[j];
            }
        }
        if (chunk == 7 && tid == 0) {    // cls key
            const half_t* kp = khcls + bh * 32;
            float s = 0.f;
#pragma unroll
            for (int d = 0; d < 32; ++d) s += q[d] * (float)kp[d];
            float pp = exp2f(s - SM_BIAS);
            l += pp;
            const half_t* vp = vplain + ((size_t)bh * NTOK + LWIN) * 32;
#pragma unroll
            for (int d = 0; d < 32; ++d) o[d] += pp * (float)vp[d];
        }
        // wave butterfly reduce
#pragma unroll
        for (int off = 1; off < 64; off <<= 1) {
            l += __shfl_xor(l, off);
#pragma unroll
            for (int d = 0; d < 32; ++d) o[d] += __shfl_xor(o[d], off);
        }
        // cross-wave via LDS (alias KV)
        float* red = (float*)&KV[0][0];
        if (lane == 0) {
#pragma unroll
            for (int d = 0; d < 32; ++d) red[wv * 33 + d] = o[d];
            red[wv * 33 + 32] = l;
        }
        __syncthreads();
        if (tid < 33) {
            float s = red[tid] + red[33 + tid] + red[66 + tid] + red[99 + tid];
            clspart[(bh * 8 + chunk) * 33 + tid] = s;
        }
        return;
    }

    // ---------------- window-attention block ----------------
    // swizzle: 1568 = 8 * 196; XCD k gets contiguous chunk of 196 blocks
    const int sw = (id & 7) * 196 + (id >> 3);
    const int wi = sw % 49;
    const int bh = sw / 49;
    const int b = bh >> 3, nh = bh & 7;

    const int g = lane >> 4, qi = lane & 15;
    const int qrow = wi * 64 + wv * 16 + qi;

    half8 aq = *(const half8*)(qh + ((size_t)bh * NTOK + qrow) * 32 + g * 8);
    float qf[8];
#pragma unroll
    for (int j = 0; j < 8; ++j) qf[j] = (float)aq[j];
    float kcls[8], vcls[2][4];
#pragma unroll
    for (int j = 0; j < 8; ++j) kcls[j] = (float)khcls[bh * 32 + g * 8 + j];
    {
        const half_t* vcb = vplain + ((size_t)bh * NTOK + LWIN) * 32;
#pragma unroll
        for (int h2 = 0; h2 < 2; ++h2)
#pragma unroll
            for (int r = 0; r < 4; ++r) vcls[h2][r] = (float)vcb[h2 * 16 + g * 4 + r];
    }

    float lacc = 0.f;
    f32x4 acc[2] = {{0.f,0.f,0.f,0.f},{0.f,0.f,0.f,0.f}};

    const int* mrow = mask + (b * WINNUM + wi) * WINNUM;
    int mv = (lane < WINNUM) ? mrow[lane] : 0;
    unsigned long long rem = __ballot(mv != 0);

    const int4* kwin = (const int4*)(kh + (size_t)bh * (WINNUM * 2560));
    const int4* vwin = (const int4*)(vh + (size_t)bh * (WINNUM * 2560));

    int4 r0, r1, r2;
    auto issue = [&](int wj) {
        const int4* kg4 = kwin + wj * 320;
        const int4* vg4 = vwin + wj * 320;
        r0 = kg4[tid];
        r1 = (tid < 64) ? kg4[tid + 256] : vg4[tid - 64];
        if (tid < 128) r2 = vg4[tid + 192];
    };
    auto commit = [&](int bu) {
        KV[bu][tid] = r0;
        KV[bu][tid + 256] = r1;
        if (tid < 128) KV[bu][tid + 512] = r2;
    };

    int buf = 0;
    if (rem) { issue(__builtin_ctzll(rem)); commit(0); }
    __syncthreads();

    while (rem) {
        rem &= rem - 1;
        if (rem) issue(__builtin_ctzll(rem));   // loads for NEXT window in flight

        const short* Kb = (const short*)&KV[buf][0];
        const short* Vb = (const short*)&KV[buf][320];

        // S^T tiles: st[t4] covers keys 16*t4.. for query column qi
        f32x4 st[4];
        __builtin_amdgcn_s_setprio(1);
#pragma unroll
        for (int t4 = 0; t4 < 4; ++t4) {
            half8 ak = *(const half8*)&Kb[(t4 * 16 + qi) * 40 + g * 8];
            st[t4] = __builtin_amdgcn_mfma_f32_16x16x32_f16(ak, aq, (f32x4){0.f,0.f,0.f,0.f}, 0, 0, 0);
        }
        __builtin_amdgcn_s_setprio(0);
        // fixed-bias softmax: p = exp2(s - SM_BIAS); l reduce deferred
        float p[4][4];
#pragma unroll
        for (int t4 = 0; t4 < 4; ++t4)
#pragma unroll
            for (int r = 0; r < 4; ++r) {
                p[t4][r] = exp2f(st[t4][r] - SM_BIAS);
                lacc += p[t4][r];
            }
        // P -> LDS fp16 (cvt_pkrtz pairs along key)
        {
            short* pw = &Plds[wv][qi * 72];
#pragma unroll
            for (int t4 = 0; t4 < 4; ++t4)
#pragma unroll
                for (int r2 = 0; r2 < 2; ++r2)
                    *(unsigned*)&pw[t4 * 16 + g * 4 + r2 * 2] = pack2(p[t4][2 * r2], p[t4][2 * r2 + 1]);
        }
        // O^T += V^T . P^T
        __builtin_amdgcn_s_setprio(1);
#pragma unroll
        for (int s2 = 0; s2 < 2; ++s2) {
            half8 bp = *(const half8*)&Plds[wv][qi * 72 + s2 * 32 + g * 8];
#pragma unroll
            for (int h2 = 0; h2 < 2; ++h2) {
                half8 av = *(const half8*)&Vb[(h2 * 16 + qi) * 80 + s2 * 32 + g * 8];
                acc[h2] = __builtin_amdgcn_mfma_f32_16x16x32_f16(av, bp, acc[h2], 0, 0, 0);
            }
        }
        __builtin_amdgcn_s_setprio(0);

        if (rem) commit(buf ^ 1);
        __syncthreads();
        buf ^= 1;
    }

    // cls key (fp32 scalar, same bias)
    float pc;
    {
        float sc = 0.f;
#pragma unroll
        for (int j = 0; j < 8; ++j) sc += qf[j] * kcls[j];
        sc += __shfl_xor(sc, 16);
        sc += __shfl_xor(sc, 32);
        pc = exp2f(sc - SM_BIAS);
    }
    // final l reduction across the 4 g-lanes, + cls
    lacc += __shfl_xor(lacc, 16);
    lacc += __shfl_xor(lacc, 32);
    float l = lacc + pc;
#pragma unroll
    for (int h2 = 0; h2 < 2; ++h2)
#pragma unroll
        for (int r = 0; r < 4; ++r) acc[h2][r] += pc * vcls[h2][r];

    // write O to t[pix][nh*32 + d], d = 16*h2 + 4*g + r
    {
        float inv = 1.f / l;
        int kk = wv * 16 + qi;
        int hh = (wi / 7) * 8 + (kk >> 3);
        int ww = (wi % 7) * 8 + (kk & 7);
        size_t pix = (size_t)b * LWIN + hh * 56 + ww;
        half_t* tp = tg + pix * 256 + nh * 32;
#pragma unroll
        for (int h2 = 0; h2 < 2; ++h2) {
            half4 hv;
#pragma unroll
            for (int r = 0; r < 4; ++r) hv[r] = (half_t)(acc[h2][r] * inv);
            *(half4*)(tp + h2 * 16 + g * 4) = hv;
        }
    }
}

// ---------------------------------------------------------------------------
// lepe_add: t[pix][c..c+7] += depthwise3x3(v) + lepe_b. Block 1568 instead
// normalizes cls partials into th cls rows.
// ---------------------------------------------------------------------------
__global__ __launch_bounds__(256)
void lepe_add(const half_t* __restrict__ vplain, const float* __restrict__ lk,
              const float* __restrict__ lb, const float* __restrict__ clspart,
              half_t* __restrict__ tg)
{
    if (blockIdx.x == 1568) {
        const int c = threadIdx.x;           // channel 0..255
        const int nh = c >> 5, d = c & 31;
#pragma unroll
        for (int b = 0; b < 4; ++b) {
            int bh = b * NH + nh;
            float os = 0.f, ls = 0.f;
#pragma unroll
            for (int ch = 0; ch < 8; ++ch) {
                os += clspart[(bh * 8 + ch) * 33 + d];
                ls += clspart[(bh * 8 + ch) * 33 + 32];
            }
            tg[(size_t)(NPIX + b) * 256 + c] = (half_t)(os / ls);
        }
        return;
    }
    const int gidx = blockIdx.x * 256 + threadIdx.x;   // NPIX*32 total
    const int pix = gidx >> 5, cg = gidx & 31;
    const int c0 = cg * 8;
    const int b = pix / LWIN, p = pix - b * LWIN;
    const int hh = p / 56, ww = p - hh * 56;
    const int nh = c0 >> 5, d0 = c0 & 31;
    const half_t* vb = vplain + (size_t)(b * NH + nh) * NTOK * 32 + d0;

    float s[8];
#pragma unroll
    for (int j = 0; j < 8; ++j) s[j] = lb[c0 + j];
#pragma unroll
    for (int dh = -1; dh <= 1; ++dh) {
        int hn = hh + dh;
        if (hn < 0 || hn >= 56) continue;
#pragma unroll
        for (int dw = -1; dw <= 1; ++dw) {
            int wn = ww + dw;
            if (wn < 0 || wn >= 56) continue;
            int tok = ((hn >> 3) * 7 + (wn >> 3)) * 64 + ((hn & 7) << 3) + (wn & 7);
            half8 vv = *(const half8*)(vb + (size_t)tok * 32);
            const float* kk = lk + ((dh + 1) * 3 + (dw + 1)) * 256 + c0;
#pragma unroll
            for (int j = 0; j < 8; ++j) s[j] += (float)vv[j] * kk[j];
        }
    }
    half_t* tp = tg + (size_t)pix * 256 + c0;
    half8 cur = *(const half8*)tp;
    half8 outv;
#pragma unroll
    for (int j = 0; j < 8; ++j) outv[j] = (half_t)((float)cur[j] + s[j]);
    *(half8*)tp = outv;
}

// ---------------------------------------------------------------------------
// out_gemm: out = t @ Wo + bo (fp16 MFMA, fp32 out), reg-staged buffers.
// ---------------------------------------------------------------------------
__global__ __launch_bounds__(256)
void out_gemm(const half_t* __restrict__ th, const half_t* __restrict__ Bt,
              const float* __restrict__ bo, float* __restrict__ out)
{
    __shared__ __align__(16) short As[2][128 * 40];
    __shared__ __align__(16) short Bs[2][128 * 40];
    const int m0 = blockIdx.y * 128, n0 = blockIdx.x * 128;
    const int tid = threadIdx.x;
    const int lane = tid & 63, wv = tid >> 6;
    const int wm = wv >> 1, wn = wv & 1;
    const int qi = lane & 15, g = lane >> 4;
    f32x4 acc[4][4] = {};

    int4 ra[2], rb[2];
    auto issue = [&](int k0) {
#pragma unroll
        for (int i = 0; i < 2; ++i) {
            int ch = tid + 256 * i;
            int row = ch >> 2, kc = (ch & 3) * 8;
            int m = m0 + row;
            ra[i] = (m < MROWS) ? *(const int4*)(th + (size_t)m * 256 + k0 + kc)
                                : make_int4(0, 0, 0, 0);
            rb[i] = *(const int4*)(Bt + (size_t)(n0 + row) * 256 + k0 + kc);
        }
    };
    auto commit = [&](int bu) {
#pragma unroll
        for (int i = 0; i < 2; ++i) {
            int ch = tid + 256 * i;
            int row = ch >> 2, kc = (ch & 3) * 8;
            *(int4*)&As[bu][row * 40 + kc] = ra[i];
            *(int4*)&Bs[bu][row * 40 + kc] = rb[i];
        }
    };

    issue(0); commit(0);
    __syncthreads();
    int buf = 0;
    for (int s = 0; s < 8; ++s) {
        if (s < 7) issue((s + 1) * 32);
        half8 af[4], bf[4];
#pragma unroll
        for (int f = 0; f < 4; ++f) {
            af[f] = *(const half8*)&As[buf][(wm * 64 + f * 16 + qi) * 40 + g * 8];
            bf[f] = *(const half8*)&Bs[buf][(wn * 64 + f * 16 + qi) * 40 + g * 8];
        }
#pragma unroll
        for (int fm = 0; fm < 4; ++fm)
#pragma unroll
            for (int fn = 0; fn < 4; ++fn)
                acc[fm][fn] = __builtin_amdgcn_mfma_f32_16x16x32_f16(af[fm], bf[fn], acc[fm][fn], 0, 0, 0);
        if (s < 7) commit(buf ^ 1);
        __syncthreads();
        buf ^= 1;
    }

    float bov[4];
    int nn[4];
#pragma unroll
    for (int fn = 0; fn < 4; ++fn) {
        nn[fn] = n0 + wn * 64 + fn * 16 + qi;
        bov[fn] = bo[nn[fn]];
    }
#pragma unroll
    for (int fm = 0; fm < 4; ++fm)
#pragma unroll
        for (int r = 0; r < 4; ++r) {
            int m = m0 + wm * 64 + fm * 16 + g * 4 + r;
            if (m >= MROWS) continue;
#pragma unroll
            for (int fn = 0; fn < 4; ++fn)
                out[(size_t)m * 256 + nn[fn]] = acc[fm][fn][r] + bov[fn];
        }
}

// ---------------------------------------------------------------------------
extern "C" void kernel_launch(void* const* d_in, const int* in_sizes, int n_in,
                              void* d_out, int out_size, void* d_ws, size_t ws_size,
                              hipStream_t stream)
{
    const float* x    = (const float*)d_in[0];
    const float* cls  = (const float*)d_in[1];
    const int*   mask = (const int*)d_in[2];
    const float* Wqkv = (const float*)d_in[5];
    const float* bqkv = (const float*)d_in[6];
    const float* Wo   = (const float*)d_in[7];
    const float* bo   = (const float*)d_in[8];
    const float* lk   = (const float*)d_in[9];
    const float* lb   = (const float*)d_in[10];
    float* out = (float*)d_out;

    char* w = (char*)d_ws;
    half_t* xh     = (half_t*)w;  w += 6424576;   // 12548*256*2
    half_t* qh     = (half_t*)w;  w += 6424576;   // 32*3137*32*2
    half_t* kh     = (half_t*)w;  w += 8028160;   // 32*49*2560*2
    half_t* khcls  = (half_t*)w;  w += 2048;      // 32*32*2
    half_t* vh     = (half_t*)w;  w += 8028160;   // 32*49*2560*2
    half_t* vplain = (half_t*)w;  w += 6424576;
    half_t* Wqkvt  = (half_t*)w;  w += 393216;    // 768*256*2
    half_t* Wot    = (half_t*)w;  w += 131072;    // 256*256*2
    half_t* th     = (half_t*)w;  w += 6424576;   // 12548*256*2
    float*  clspart= (float*)w;   w += 33792;     // 32*8*33*4

    prep<<<1600, 256, 0, stream>>>(x, cls, Wqkv, Wo, xh, Wqkvt, Wot);
    qkv_gemm<<<dim3(6, 99), 256, 0, stream>>>(xh, Wqkvt, bqkv, qh, kh, khcls, vh, vplain);
    win_attn<<<1824, 256, 0, stream>>>(qh, kh, khcls, vh, vplain, mask, th, clspart);
    lepe_add<<<1569, 256, 0, stream>>>(vplain, lk, lb, clspart, th);
    out_gemm<<<dim3(2, 99), 256, 0, stream>>>(th, Wot, bo, out);
}